// Round 7
// baseline (795.386 us; speedup 1.0000x reference)
//
#include <hip/hip_runtime.h>
#include <hip/hip_bf16.h>

#define N_TOK 8192
#define D_DIM 1024
#define E_NUM 8
#define H_DIM 2730
#define HP    2816     // 22*128 padded h-cols
#define NP    5632     // 2*HP = interleaved B' rows
#define NROWS (N_TOK*2)
#define MAXT256  72    // sum ceil(ne/256) <= 16384/256 + 7 = 71

typedef __bf16 bf16;
typedef __bf16 bf16x8 __attribute__((ext_vector_type(8)));
typedef __bf16 bf16x4 __attribute__((ext_vector_type(4)));
typedef float  f32x4  __attribute__((ext_vector_type(4)));

__device__ __forceinline__ void gload_lds16(const bf16* g, bf16* l) {
  __builtin_amdgcn_global_load_lds((const __attribute__((address_space(1))) void*)g,
                                   (__attribute__((address_space(3))) void*)l, 16, 0, 0);
}
#define VMCNT(n) asm volatile("s_waitcnt vmcnt(" #n ")" ::: "memory")
#define BAR() __builtin_amdgcn_s_barrier()

// ---------- conv: build interleaved B' [e][5632][1024] bf16 ----------
__global__ void conv13_kernel(const float* __restrict__ w1, const float* __restrict__ w3,
                              bf16* __restrict__ Bp) {
  int i = blockIdx.x * blockDim.x + threadIdx.x;      // (e, r', c8)
  if (i >= E_NUM * NP * 128) return;
  int c8 = i & 127;
  int r  = (i >> 7) % NP;
  int e  = i / (NP * 128);
  int hc = ((r >> 5) << 4) + (r & 15);
  bf16x8 o;
  if (hc < H_DIM) {
    const float* s = (((r >> 4) & 1) ? w3 : w1) + ((long)e * H_DIM + hc) * D_DIM + c8 * 8;
    float4 a0 = ((const float4*)s)[0], a1 = ((const float4*)s)[1];
    o[0]=(bf16)a0.x; o[1]=(bf16)a0.y; o[2]=(bf16)a0.z; o[3]=(bf16)a0.w;
    o[4]=(bf16)a1.x; o[5]=(bf16)a1.y; o[6]=(bf16)a1.z; o[7]=(bf16)a1.w;
  } else {
    #pragma unroll
    for (int j = 0; j < 8; j++) o[j] = (bf16)0.f;
  }
  ((bf16x8*)Bp)[i] = o;
}

__global__ void conv_w2_kernel(const float* __restrict__ src, bf16* __restrict__ dst) {
  int i = blockIdx.x * blockDim.x + threadIdx.x;      // row*(HP/8) + c8
  if (i >= E_NUM * D_DIM * (HP / 8)) return;
  int c8 = i % (HP / 8);
  int row = i / (HP / 8);
  int c = c8 * 8;
  const float* s = src + (long)row * H_DIM + c;
  bf16x8 o;
  #pragma unroll
  for (int j = 0; j < 8; j++) o[j] = (c + j < H_DIM) ? (bf16)s[j] : (bf16)0.f;
  ((bf16x8*)dst)[i] = o;
}

// ---------------- router ----------------
__global__ void router_kernel(const float* __restrict__ x, const float* __restrict__ gw,
                              int* __restrict__ topi, float* __restrict__ topw,
                              int* __restrict__ counts) {
  int t = blockIdx.x * (blockDim.x >> 6) + (threadIdx.x >> 6);
  int lane = threadIdx.x & 63;
  if (t >= N_TOK) return;
  const float* xr = x + (long)t * D_DIM;
  float acc[E_NUM];
  #pragma unroll
  for (int e = 0; e < E_NUM; e++) acc[e] = 0.f;
  for (int j = 0; j < D_DIM / 64; j++) {
    float xv = xr[j * 64 + lane];
    #pragma unroll
    for (int e = 0; e < E_NUM; e++) acc[e] += xv * gw[e * D_DIM + j * 64 + lane];
  }
  #pragma unroll
  for (int e = 0; e < E_NUM; e++) {
    float v = acc[e];
    #pragma unroll
    for (int s = 32; s > 0; s >>= 1) v += __shfl_xor(v, s, 64);
    acc[e] = v;
  }
  if (lane == 0) {
    int b0 = -1, b1 = -1; float v0 = -1e30f, v1 = -1e30f;
    #pragma unroll
    for (int e = 0; e < E_NUM; e++) {
      float v = acc[e];
      if (v > v0) { v1 = v0; b1 = b0; v0 = v; b0 = e; }
      else if (v > v1) { v1 = v; b1 = e; }
    }
    float w0 = 1.f / (1.f + expf(v1 - v0));
    topi[t * 2] = b0; topi[t * 2 + 1] = b1;
    topw[t * 2] = w0; topw[t * 2 + 1] = 1.f - w0;
    atomicAdd(&counts[b0], 1); atomicAdd(&counts[b1], 1);
  }
}

// offsets + 256-row tile list
__global__ void tiles_kernel(const int* __restrict__ counts, int* __restrict__ offs,
                             int* __restrict__ tlist2) {
  if (threadIdx.x == 0) {
    int s = 0, idx2 = 0;
    for (int e = 0; e < E_NUM; e++) {
      offs[e] = s;
      int ne = counts[e];
      s += ne;
      int nt2 = (ne + 255) >> 8;
      for (int t = 0; t < nt2; t++) tlist2[idx2++] = (e << 8) | t;
    }
    offs[E_NUM] = s;
    for (; idx2 < MAXT256; idx2++) tlist2[idx2] = -1;
  }
}

__global__ void scatter_kernel(const int* __restrict__ topi, const float* __restrict__ topw,
                               const int* __restrict__ offs, int* __restrict__ cursor,
                               int* __restrict__ rowmap, float* __restrict__ roww,
                               int* __restrict__ rowoftok) {
  int i = blockIdx.x * blockDim.x + threadIdx.x;
  if (i >= NROWS) return;
  int e = topi[i];
  int pos = atomicAdd(&cursor[e], 1);
  int row = offs[e] + pos;
  rowmap[row] = i >> 1;
  roww[row] = topw[i];
  rowoftok[i] = row;
}

__global__ void gather_kernel(const float* __restrict__ x, const int* __restrict__ rowmap,
                              bf16* __restrict__ Xg) {
  int r = blockIdx.x * (blockDim.x >> 6) + (threadIdx.x >> 6);
  int lane = threadIdx.x & 63;
  if (r >= NROWS) return;
  int t = rowmap[r];
  const float4* src = (const float4*)(x + (long)t * D_DIM);
  bf16x4* dst = (bf16x4*)(Xg + (long)r * D_DIM);
  #pragma unroll
  for (int j = 0; j < 4; j++) {
    float4 v = src[j * 64 + lane];
    bf16x4 o; o[0]=(bf16)v.x; o[1]=(bf16)v.y; o[2]=(bf16)v.z; o[3]=(bf16)v.w;
    dst[j * 64 + lane] = o;
  }
}

// combine: out[t] = w0*y[r0] + w1*y[r1]
__global__ void combine_kernel(const bf16* __restrict__ y, const int* __restrict__ rowoftok,
                               const float* __restrict__ topw, float* __restrict__ out) {
  int t = blockIdx.x * (blockDim.x >> 6) + (threadIdx.x >> 6);
  int lane = threadIdx.x & 63;
  if (t >= N_TOK) return;
  int r0 = rowoftok[t * 2], r1 = rowoftok[t * 2 + 1];
  float w0 = topw[t * 2], w1 = topw[t * 2 + 1];
  const bf16x8* y0 = (const bf16x8*)(y + (long)r0 * D_DIM);
  const bf16x8* y1 = (const bf16x8*)(y + (long)r1 * D_DIM);
  float* o = out + (long)t * D_DIM;
  #pragma unroll
  for (int j = 0; j < 2; j++) {
    bf16x8 a = y0[j * 64 + lane], b = y1[j * 64 + lane];
    float4 v0, v1;
    v0.x = w0*(float)a[0] + w1*(float)b[0]; v0.y = w0*(float)a[1] + w1*(float)b[1];
    v0.z = w0*(float)a[2] + w1*(float)b[2]; v0.w = w0*(float)a[3] + w1*(float)b[3];
    v1.x = w0*(float)a[4] + w1*(float)b[4]; v1.y = w0*(float)a[5] + w1*(float)b[5];
    v1.z = w0*(float)a[6] + w1*(float)b[6]; v1.w = w0*(float)a[7] + w1*(float)b[7];
    float4* op = (float4*)(o + (j * 64 + lane) * 8);
    op[0] = v0; op[1] = v1;
  }
}

// ================== shared 256x256 BK=32 ring-4 GEMM structure ==================
// LDS: A slots [4][8192 elems] @0, B slots [4][8192] @32768 (128 KB total).
// Stage 3 tiles ahead; vmcnt(12) = 3 groups x 4 loads in flight; tail 8/4/0.
// Per tile: ph0 {read A-half0 (4) + B (4), 16 MFMA}, ph1 {read A-half1 (4), 16 MFMA}.
// Source-quarter swizzle (r3-verified, conflicts=0): stage fetches quarter
// (lane&3)^((lane>>3)&3); read uses quarter hi^((fr>>1)&3).

#define STAGE4(T) do { int sb_ = ((T) & 3) * 8192; \
    gload_lds16(aSrc0 + (T) * 32, smem + sb_ + wv * 512); \
    gload_lds16(aSrc1 + (T) * 32, smem + sb_ + 4096 + wv * 512); \
    gload_lds16(bSrc0 + (T) * 32, smem + 32768 + sb_ + wv * 512); \
    gload_lds16(bSrc1 + (T) * 32, smem + 32768 + sb_ + 4096 + wv * 512); \
  } while (0)

#define PH0(SB) do { \
    bf16x8 aF[4]; \
    _Pragma("unroll") for (int m_ = 0; m_ < 4; m_++) \
      aF[m_] = *(const bf16x8*)&smem[(SB) + (wr * 64 + m_ * 16 + fr) * 32 + qp]; \
    _Pragma("unroll") for (int q_ = 0; q_ < 4; q_++) \
      bF[q_] = *(const bf16x8*)&smem[32768 + (SB) + ((q_ >> 1) * 128 + wc * 32 + (q_ & 1) * 16 + fr) * 32 + qp]; \
    __builtin_amdgcn_s_setprio(1); \
    _Pragma("unroll") for (int m_ = 0; m_ < 4; m_++) \
    _Pragma("unroll") for (int q_ = 0; q_ < 4; q_++) \
      acc[0][q_ >> 1][m_][q_ & 1] = __builtin_amdgcn_mfma_f32_16x16x32_bf16(aF[m_], bF[q_], acc[0][q_ >> 1][m_][q_ & 1], 0, 0, 0); \
    __builtin_amdgcn_s_setprio(0); \
  } while (0)

#define PH1(SB) do { \
    bf16x8 aF[4]; \
    _Pragma("unroll") for (int m_ = 0; m_ < 4; m_++) \
      aF[m_] = *(const bf16x8*)&smem[(SB) + (128 + wr * 64 + m_ * 16 + fr) * 32 + qp]; \
    __builtin_amdgcn_s_setprio(1); \
    _Pragma("unroll") for (int m_ = 0; m_ < 4; m_++) \
    _Pragma("unroll") for (int q_ = 0; q_ < 4; q_++) \
      acc[1][q_ >> 1][m_][q_ & 1] = __builtin_amdgcn_mfma_f32_16x16x32_bf16(aF[m_], bF[q_], acc[1][q_ >> 1][m_][q_ & 1], 0, 0, 0); \
    __builtin_amdgcn_s_setprio(0); \
  } while (0)

#define GEMM_PREAMBLE() \
  int tid = threadIdx.x, wv = tid >> 6, lane = tid & 63; \
  int wr = wv >> 2, wc = wv & 3; \
  int fr = lane & 15, hi = lane >> 4; \
  int qp = (hi ^ ((fr >> 1) & 3)) * 8; \
  int srcq = ((lane & 3) ^ ((lane >> 3) & 3)) * 8; \
  int srow = lane >> 2; \
  f32x4 acc[2][2][4][2]; \
  _Pragma("unroll") for (int a = 0; a < 2; a++) \
  _Pragma("unroll") for (int b = 0; b < 2; b++) \
  _Pragma("unroll") for (int m = 0; m < 4; m++) \
  _Pragma("unroll") for (int n = 0; n < 2; n++) acc[a][b][m][n] = (f32x4)0.f; \
  bf16x8 bF[4];

// ---------------- GEMM1: h' = silu(Xg*B'^T gate) * up, K=1024 (32 tiles) ------
__global__ __launch_bounds__(512, 2) void gemm1_kernel(
    const bf16* __restrict__ Xg, const bf16* __restrict__ Bp,
    const int* __restrict__ counts, const int* __restrict__ offs,
    const int* __restrict__ tlist2, bf16* __restrict__ h) {
  int te = tlist2[blockIdx.x];
  if (te < 0) return;
  int e = te >> 8, tm = te & 255;
  int ne = counts[e];
  int row_base = offs[e];
  int n0 = blockIdx.y * 256;

  __shared__ bf16 smem[65536];
  GEMM_PREAMBLE();

  const bf16* Bpe = Bp + (long)e * NP * D_DIM;
  int ra0 = row_base + min(tm * 256 + wv * 16 + srow, ne - 1);
  int ra1 = row_base + min(tm * 256 + 128 + wv * 16 + srow, ne - 1);
  const bf16* aSrc0 = Xg + (long)ra0 * D_DIM + srcq;
  const bf16* aSrc1 = Xg + (long)ra1 * D_DIM + srcq;
  const bf16* bSrc0 = Bpe + (long)(n0 + wv * 16 + srow) * D_DIM + srcq;
  const bf16* bSrc1 = Bpe + (long)(n0 + 128 + wv * 16 + srow) * D_DIM + srcq;

  STAGE4(0); STAGE4(1); STAGE4(2);
  for (int t = 0; t < 29; t++) {
    STAGE4(t + 3);
    VMCNT(12); BAR();
    int sb = (t & 3) * 8192;
    PH0(sb); BAR();
    PH1(sb); BAR();
  }
  { VMCNT(8); BAR(); int sb = (29 & 3) * 8192; PH0(sb); BAR(); PH1(sb); BAR(); }
  { VMCNT(4); BAR(); int sb = (30 & 3) * 8192; PH0(sb); BAR(); PH1(sb); BAR(); }
  { VMCNT(0); BAR(); int sb = (31 & 3) * 8192; PH0(sb); BAR(); PH1(sb); }

  // epilogue: frag n=0 = gate, n=1 = up (B' 16-row interleave)
  int crow4 = hi * 4;
  #pragma unroll
  for (int mh = 0; mh < 2; mh++)
    #pragma unroll
    for (int m = 0; m < 4; m++)
      #pragma unroll
      for (int j = 0; j < 4; j++) {
        int rloc = tm * 256 + mh * 128 + wr * 64 + m * 16 + crow4 + j;
        if (rloc < ne) {
          long hrow = (long)(row_base + rloc) * HP;
          #pragma unroll
          for (int nh = 0; nh < 2; nh++) {
            int hc0 = (n0 + nh * 128 + wc * 32) >> 1;
            float g = acc[mh][nh][m][0][j], u = acc[mh][nh][m][1][j];
            h[hrow + hc0 + fr] = (bf16)((g / (1.f + __expf(-g))) * u);
          }
        }
      }
}

// ---------------- GEMM2: y = h*w2^T, K=2816 (88 tiles) ----------------
__global__ __launch_bounds__(512, 2) void gemm2_kernel(
    const bf16* __restrict__ h, const bf16* __restrict__ w2b,
    const int* __restrict__ counts, const int* __restrict__ offs,
    const int* __restrict__ tlist2, bf16* __restrict__ y) {
  int te = tlist2[blockIdx.x];
  if (te < 0) return;
  int e = te >> 8, tm = te & 255;
  int ne = counts[e];
  int row_base = offs[e];
  int n0 = blockIdx.y * 256;

  __shared__ bf16 smem[65536];
  GEMM_PREAMBLE();

  const bf16* w2e = w2b + (long)e * D_DIM * HP;
  int ra0 = row_base + min(tm * 256 + wv * 16 + srow, ne - 1);
  int ra1 = row_base + min(tm * 256 + 128 + wv * 16 + srow, ne - 1);
  const bf16* aSrc0 = h + (long)ra0 * HP + srcq;
  const bf16* aSrc1 = h + (long)ra1 * HP + srcq;
  const bf16* bSrc0 = w2e + (long)(n0 + wv * 16 + srow) * HP + srcq;
  const bf16* bSrc1 = w2e + (long)(n0 + 128 + wv * 16 + srow) * HP + srcq;

  STAGE4(0); STAGE4(1); STAGE4(2);
  for (int t = 0; t < 85; t++) {
    STAGE4(t + 3);
    VMCNT(12); BAR();
    int sb = (t & 3) * 8192;
    PH0(sb); BAR();
    PH1(sb); BAR();
  }
  { VMCNT(8); BAR(); int sb = (85 & 3) * 8192; PH0(sb); BAR(); PH1(sb); BAR(); }
  { VMCNT(4); BAR(); int sb = (86 & 3) * 8192; PH0(sb); BAR(); PH1(sb); BAR(); }
  { VMCNT(0); BAR(); int sb = (87 & 3) * 8192; PH0(sb); BAR(); PH1(sb); }

  int crow4 = hi * 4;
  #pragma unroll
  for (int mh = 0; mh < 2; mh++)
    #pragma unroll
    for (int m = 0; m < 4; m++)
      #pragma unroll
      for (int j = 0; j < 4; j++) {
        int rloc = tm * 256 + mh * 128 + wr * 64 + m * 16 + crow4 + j;
        if (rloc < ne) {
          long yrow = (long)(row_base + rloc) * D_DIM;
          #pragma unroll
          for (int nh = 0; nh < 2; nh++)
            #pragma unroll
            for (int n = 0; n < 2; n++) {
              int col = n0 + nh * 128 + wc * 32 + n * 16 + fr;
              y[yrow + col] = (bf16)acc[mh][nh][m][n][j];
            }
        }
      }
}

extern "C" void kernel_launch(void* const* d_in, const int* in_sizes, int n_in,
                              void* d_out, int out_size, void* d_ws, size_t ws_size,
                              hipStream_t stream) {
  const float* x  = (const float*)d_in[0];
  const float* gw = (const float*)d_in[1];
  const float* w1 = (const float*)d_in[2];
  const float* w3 = (const float*)d_in[3];
  const float* w2 = (const float*)d_in[4];
  float* out = (float*)d_out;

  char* ws = (char*)d_ws;
  int*   counts   = (int*)(ws);
  int*   cursor   = (int*)(ws + 64);
  int*   offs     = (int*)(ws + 128);
  int*   tlist2   = (int*)(ws + 768);              // 288 B
  int*   topi     = (int*)(ws + 2048);
  float* topw     = (float*)(ws + 2048 + 65536);
  int*   rowmap   = (int*)(ws + 2048 + 131072);
  float* roww     = (float*)(ws + 2048 + 196608);
  int*   rowoftok = (int*)(ws + 2048 + 262144);
  char*  big      = ws + 2048 + 327680;
  // Bp (92.3 MB) and w2b (46.1 MB) share a region: conv_w2 runs AFTER gemm1.
  bf16* Bp   = (bf16*)big;                                   // [8][5632][1024]
  bf16* w2b  = (bf16*)big;                                   // [8][1024][2816] (alias)
  bf16* Xg   = Bp + (size_t)E_NUM * NP * D_DIM;              // [16384][1024]
  bf16* hbuf = Xg + (size_t)NROWS * D_DIM;                   // [16384][2816]
  bf16* ybuf = Xg;                                           // alias (Xg dead after gemm1)

  hipMemsetAsync((char*)d_out + (size_t)(out_size - 1) * sizeof(float), 0, sizeof(float), stream);
  hipMemsetAsync(ws, 0, 256, stream);   // counts, cursor

  int nbp = E_NUM * NP * 128;
  conv13_kernel<<<(nbp + 255) / 256, 256, 0, stream>>>(w1, w3, Bp);

  router_kernel<<<N_TOK / 4, 256, 0, stream>>>(x, gw, topi, topw, counts);
  tiles_kernel<<<1, 64, 0, stream>>>(counts, offs, tlist2);
  scatter_kernel<<<(NROWS + 255) / 256, 256, 0, stream>>>(topi, topw, offs, cursor, rowmap, roww, rowoftok);
  gather_kernel<<<NROWS / 4, 256, 0, stream>>>(x, rowmap, Xg);

  dim3 g1(MAXT256, NP / 256);      // (72, 22)
  gemm1_kernel<<<g1, 512, 0, stream>>>(Xg, Bp, counts, offs, tlist2, hbuf);

  int w2n = E_NUM * D_DIM * (HP / 8);
  conv_w2_kernel<<<(w2n + 255) / 256, 256, 0, stream>>>(w2, w2b);

  dim3 g2(MAXT256, D_DIM / 256);   // (72, 4)
  gemm2_kernel<<<g2, 512, 0, stream>>>(hbuf, w2b, counts, offs, tlist2, ybuf);
  combine_kernel<<<N_TOK / 4, 256, 0, stream>>>(ybuf, rowoftok, topw, out);
}

// Round 8
// 758.859 us; speedup vs baseline: 1.0481x; 1.0481x over previous
//
#include <hip/hip_runtime.h>
#include <hip/hip_bf16.h>

#define N_TOK 8192
#define D_DIM 1024
#define E_NUM 8
#define H_DIM 2730
#define HP    2816     // 22*128 padded h-cols
#define NP    5632     // 2*HP = interleaved B' rows
#define NROWS (N_TOK*2)
#define MAXTILES 136   // sum ceil(ne/128) <= 135
#define MAXT256  72    // sum ceil(ne/256) <= 71

typedef __bf16 bf16;
typedef __bf16 bf16x8 __attribute__((ext_vector_type(8)));
typedef __bf16 bf16x4 __attribute__((ext_vector_type(4)));
typedef float  f32x4  __attribute__((ext_vector_type(4)));

__device__ __forceinline__ void gload_lds16(const bf16* g, bf16* l) {
  __builtin_amdgcn_global_load_lds((const __attribute__((address_space(1))) void*)g,
                                   (__attribute__((address_space(3))) void*)l, 16, 0, 0);
}
#define VMCNT(n) asm volatile("s_waitcnt vmcnt(" #n ")" ::: "memory")
#define LGKM0()  asm volatile("s_waitcnt lgkmcnt(0)" ::: "memory")
#define BAR() __builtin_amdgcn_s_barrier()

// ---------- conv: build interleaved B' [e][5632][1024] bf16 ----------
__global__ void conv13_kernel(const float* __restrict__ w1, const float* __restrict__ w3,
                              bf16* __restrict__ Bp) {
  int i = blockIdx.x * blockDim.x + threadIdx.x;      // (e, r', c8)
  if (i >= E_NUM * NP * 128) return;
  int c8 = i & 127;
  int r  = (i >> 7) % NP;
  int e  = i / (NP * 128);
  int hc = ((r >> 5) << 4) + (r & 15);
  bf16x8 o;
  if (hc < H_DIM) {
    const float* s = (((r >> 4) & 1) ? w3 : w1) + ((long)e * H_DIM + hc) * D_DIM + c8 * 8;
    float4 a0 = ((const float4*)s)[0], a1 = ((const float4*)s)[1];
    o[0]=(bf16)a0.x; o[1]=(bf16)a0.y; o[2]=(bf16)a0.z; o[3]=(bf16)a0.w;
    o[4]=(bf16)a1.x; o[5]=(bf16)a1.y; o[6]=(bf16)a1.z; o[7]=(bf16)a1.w;
  } else {
    #pragma unroll
    for (int j = 0; j < 8; j++) o[j] = (bf16)0.f;
  }
  ((bf16x8*)Bp)[i] = o;
}

__global__ void conv_w2_kernel(const float* __restrict__ src, bf16* __restrict__ dst) {
  int i = blockIdx.x * blockDim.x + threadIdx.x;      // row*(HP/8) + c8
  if (i >= E_NUM * D_DIM * (HP / 8)) return;
  int c8 = i % (HP / 8);
  int row = i / (HP / 8);
  int c = c8 * 8;
  const float* s = src + (long)row * H_DIM + c;
  bf16x8 o;
  #pragma unroll
  for (int j = 0; j < 8; j++) o[j] = (c + j < H_DIM) ? (bf16)s[j] : (bf16)0.f;
  ((bf16x8*)dst)[i] = o;
}

// ---------------- router ----------------
__global__ void router_kernel(const float* __restrict__ x, const float* __restrict__ gw,
                              int* __restrict__ topi, float* __restrict__ topw,
                              int* __restrict__ counts) {
  int t = blockIdx.x * (blockDim.x >> 6) + (threadIdx.x >> 6);
  int lane = threadIdx.x & 63;
  if (t >= N_TOK) return;
  const float* xr = x + (long)t * D_DIM;
  float acc[E_NUM];
  #pragma unroll
  for (int e = 0; e < E_NUM; e++) acc[e] = 0.f;
  for (int j = 0; j < D_DIM / 64; j++) {
    float xv = xr[j * 64 + lane];
    #pragma unroll
    for (int e = 0; e < E_NUM; e++) acc[e] += xv * gw[e * D_DIM + j * 64 + lane];
  }
  #pragma unroll
  for (int e = 0; e < E_NUM; e++) {
    float v = acc[e];
    #pragma unroll
    for (int s = 32; s > 0; s >>= 1) v += __shfl_xor(v, s, 64);
    acc[e] = v;
  }
  if (lane == 0) {
    int b0 = -1, b1 = -1; float v0 = -1e30f, v1 = -1e30f;
    #pragma unroll
    for (int e = 0; e < E_NUM; e++) {
      float v = acc[e];
      if (v > v0) { v1 = v0; b1 = b0; v0 = v; b0 = e; }
      else if (v > v1) { v1 = v; b1 = e; }
    }
    float w0 = 1.f / (1.f + expf(v1 - v0));
    topi[t * 2] = b0; topi[t * 2 + 1] = b1;
    topw[t * 2] = w0; topw[t * 2 + 1] = 1.f - w0;
    atomicAdd(&counts[b0], 1); atomicAdd(&counts[b1], 1);
  }
}

// offsets + 128-row tile list (gemm2) + 256-row tile list (gemm1)
__global__ void tiles_kernel(const int* __restrict__ counts, int* __restrict__ offs,
                             int* __restrict__ tlist, int* __restrict__ tlist2) {
  if (threadIdx.x == 0) {
    int s = 0, idx = 0, idx2 = 0;
    for (int e = 0; e < E_NUM; e++) {
      offs[e] = s;
      int ne = counts[e];
      s += ne;
      int nt = (ne + 127) >> 7;
      for (int t = 0; t < nt; t++) tlist[idx++] = (e << 8) | t;
      int nt2 = (ne + 255) >> 8;
      for (int t = 0; t < nt2; t++) tlist2[idx2++] = (e << 8) | t;
    }
    offs[E_NUM] = s;
    for (; idx < MAXTILES; idx++) tlist[idx] = -1;
    for (; idx2 < MAXT256; idx2++) tlist2[idx2] = -1;
  }
}

__global__ void scatter_kernel(const int* __restrict__ topi, const float* __restrict__ topw,
                               const int* __restrict__ offs, int* __restrict__ cursor,
                               int* __restrict__ rowmap, float* __restrict__ roww,
                               int* __restrict__ rowoftok) {
  int i = blockIdx.x * blockDim.x + threadIdx.x;
  if (i >= NROWS) return;
  int e = topi[i];
  int pos = atomicAdd(&cursor[e], 1);
  int row = offs[e] + pos;
  rowmap[row] = i >> 1;
  roww[row] = topw[i];
  rowoftok[i] = row;
}

__global__ void gather_kernel(const float* __restrict__ x, const int* __restrict__ rowmap,
                              bf16* __restrict__ Xg) {
  int r = blockIdx.x * (blockDim.x >> 6) + (threadIdx.x >> 6);
  int lane = threadIdx.x & 63;
  if (r >= NROWS) return;
  int t = rowmap[r];
  const float4* src = (const float4*)(x + (long)t * D_DIM);
  bf16x4* dst = (bf16x4*)(Xg + (long)r * D_DIM);
  #pragma unroll
  for (int j = 0; j < 4; j++) {
    float4 v = src[j * 64 + lane];
    bf16x4 o; o[0]=(bf16)v.x; o[1]=(bf16)v.y; o[2]=(bf16)v.z; o[3]=(bf16)v.w;
    dst[j * 64 + lane] = o;
  }
}

// combine: out[t] = w0*y[r0] + w1*y[r1]
__global__ void combine_kernel(const bf16* __restrict__ y, const int* __restrict__ rowoftok,
                               const float* __restrict__ topw, float* __restrict__ out) {
  int t = blockIdx.x * (blockDim.x >> 6) + (threadIdx.x >> 6);
  int lane = threadIdx.x & 63;
  if (t >= N_TOK) return;
  int r0 = rowoftok[t * 2], r1 = rowoftok[t * 2 + 1];
  float w0 = topw[t * 2], w1 = topw[t * 2 + 1];
  const bf16x8* y0 = (const bf16x8*)(y + (long)r0 * D_DIM);
  const bf16x8* y1 = (const bf16x8*)(y + (long)r1 * D_DIM);
  float* o = out + (long)t * D_DIM;
  #pragma unroll
  for (int j = 0; j < 2; j++) {
    bf16x8 a = y0[j * 64 + lane], b = y1[j * 64 + lane];
    float4 v0, v1;
    v0.x = w0*(float)a[0] + w1*(float)b[0]; v0.y = w0*(float)a[1] + w1*(float)b[1];
    v0.z = w0*(float)a[2] + w1*(float)b[2]; v0.w = w0*(float)a[3] + w1*(float)b[3];
    v1.x = w0*(float)a[4] + w1*(float)b[4]; v1.y = w0*(float)a[5] + w1*(float)b[5];
    v1.z = w0*(float)a[6] + w1*(float)b[6]; v1.w = w0*(float)a[7] + w1*(float)b[7];
    float4* op = (float4*)(o + (j * 64 + lane) * 8);
    op[0] = v0; op[1] = v1;
  }
}

// ============== GEMM schedule (r8): reads issued BEFORE the barrier ==============
// Iter t: READ0(slot t) | STAGE(t+ahead) | BAR | MFMA0 | READ1 | MFMA1 |
//         lgkmcnt(0) | VMCNT(counted) | BAR.
// Slot-t readiness established by the PREVIOUS iteration's counted vmcnt+BAR, so
// READ0 can issue early and its latency hides under the barrier wait. lgkmcnt(0)
// before the trailing BAR ensures no ds_read is in flight when the slot staged
// next iteration (ring reuse) gets overwritten. vmcnt arithmetic: gemm1 ring-4,
// 4 loads/wave/tile, 3 ahead -> steady VMCNT(8) = groups {t+2,t+3} in flight;
// gemm2 ring-3, 6 loads/wave/tile, 2 ahead -> steady VMCNT(6). Source-quarter
// swizzle (r3-verified, conflicts=0) unchanged.

// ---------------- GEMM1: 256x256, BK=32, 8 waves, ring-4 (128 KB) -------------
#define G1_STAGE(T) do { int sb_ = ((T) & 3) * 8192; \
    gload_lds16(aSrc0 + (T) * 32, smem + sb_ + wv * 512); \
    gload_lds16(aSrc1 + (T) * 32, smem + sb_ + 4096 + wv * 512); \
    gload_lds16(bSrc0 + (T) * 32, smem + 32768 + sb_ + wv * 512); \
    gload_lds16(bSrc1 + (T) * 32, smem + 32768 + sb_ + 4096 + wv * 512); \
  } while (0)

#define G1_READ0(SB) do { \
    _Pragma("unroll") for (int m_ = 0; m_ < 4; m_++) \
      aF0[m_] = *(const bf16x8*)&smem[(SB) + (wr * 64 + m_ * 16 + fr) * 32 + qp]; \
    _Pragma("unroll") for (int q_ = 0; q_ < 4; q_++) \
      bF[q_] = *(const bf16x8*)&smem[32768 + (SB) + ((q_ >> 1) * 128 + wc * 32 + (q_ & 1) * 16 + fr) * 32 + qp]; \
  } while (0)

#define G1_MFMA0() do { __builtin_amdgcn_s_setprio(1); \
    _Pragma("unroll") for (int m_ = 0; m_ < 4; m_++) \
    _Pragma("unroll") for (int q_ = 0; q_ < 4; q_++) \
      acc[0][q_ >> 1][m_][q_ & 1] = __builtin_amdgcn_mfma_f32_16x16x32_bf16(aF0[m_], bF[q_], acc[0][q_ >> 1][m_][q_ & 1], 0, 0, 0); \
    __builtin_amdgcn_s_setprio(0); } while (0)

#define G1_READ1(SB) do { \
    _Pragma("unroll") for (int m_ = 0; m_ < 4; m_++) \
      aF1[m_] = *(const bf16x8*)&smem[(SB) + (128 + wr * 64 + m_ * 16 + fr) * 32 + qp]; \
  } while (0)

#define G1_MFMA1() do { __builtin_amdgcn_s_setprio(1); \
    _Pragma("unroll") for (int m_ = 0; m_ < 4; m_++) \
    _Pragma("unroll") for (int q_ = 0; q_ < 4; q_++) \
      acc[1][q_ >> 1][m_][q_ & 1] = __builtin_amdgcn_mfma_f32_16x16x32_bf16(aF1[m_], bF[q_], acc[1][q_ >> 1][m_][q_ & 1], 0, 0, 0); \
    __builtin_amdgcn_s_setprio(0); } while (0)

__global__ __launch_bounds__(512, 2) void gemm1_kernel(
    const bf16* __restrict__ Xg, const bf16* __restrict__ Bp,
    const int* __restrict__ counts, const int* __restrict__ offs,
    const int* __restrict__ tlist2, bf16* __restrict__ h) {
  int te = tlist2[blockIdx.x];
  if (te < 0) return;
  int e = te >> 8, tm = te & 255;
  int ne = counts[e];
  int row_base = offs[e];
  int n0 = blockIdx.y * 256;

  __shared__ bf16 smem[65536];
  int tid = threadIdx.x, wv = tid >> 6, lane = tid & 63;
  int wr = wv >> 2, wc = wv & 3;
  int fr = lane & 15, hi = lane >> 4;
  int qp = (hi ^ ((fr >> 1) & 3)) * 8;
  int srcq = ((lane & 3) ^ ((lane >> 3) & 3)) * 8;
  int srow = lane >> 2;

  f32x4 acc[2][2][4][2];
  #pragma unroll
  for (int a = 0; a < 2; a++)
    #pragma unroll
    for (int b = 0; b < 2; b++)
      #pragma unroll
      for (int m = 0; m < 4; m++)
        #pragma unroll
        for (int n = 0; n < 2; n++) acc[a][b][m][n] = (f32x4)0.f;

  const bf16* Bpe = Bp + (long)e * NP * D_DIM;
  int ra0 = row_base + min(tm * 256 + wv * 16 + srow, ne - 1);
  int ra1 = row_base + min(tm * 256 + 128 + wv * 16 + srow, ne - 1);
  const bf16* aSrc0 = Xg + (long)ra0 * D_DIM + srcq;
  const bf16* aSrc1 = Xg + (long)ra1 * D_DIM + srcq;
  const bf16* bSrc0 = Bpe + (long)(n0 + wv * 16 + srow) * D_DIM + srcq;
  const bf16* bSrc1 = Bpe + (long)(n0 + 128 + wv * 16 + srow) * D_DIM + srcq;

  bf16x8 aF0[4], aF1[4], bF[4];

  G1_STAGE(0); G1_STAGE(1); G1_STAGE(2);
  VMCNT(8); BAR();

  for (int t = 0; t < 29; t++) {
    int sb = (t & 3) * 8192;
    G1_READ0(sb);
    G1_STAGE(t + 3);
    BAR();
    G1_MFMA0();
    G1_READ1(sb);
    G1_MFMA1();
    LGKM0(); VMCNT(8); BAR();
  }
  { int sb = (29 & 3) * 8192; G1_READ0(sb); BAR(); G1_MFMA0(); G1_READ1(sb); G1_MFMA1(); LGKM0(); VMCNT(4); BAR(); }
  { int sb = (30 & 3) * 8192; G1_READ0(sb); BAR(); G1_MFMA0(); G1_READ1(sb); G1_MFMA1(); LGKM0(); VMCNT(0); BAR(); }
  { int sb = (31 & 3) * 8192; G1_READ0(sb); G1_MFMA0(); G1_READ1(sb); G1_MFMA1(); }

  // epilogue: frag n=0 = gate, n=1 = up (B' 16-row interleave)
  int crow4 = hi * 4;
  #pragma unroll
  for (int mh = 0; mh < 2; mh++)
    #pragma unroll
    for (int m = 0; m < 4; m++)
      #pragma unroll
      for (int j = 0; j < 4; j++) {
        int rloc = tm * 256 + mh * 128 + wr * 64 + m * 16 + crow4 + j;
        if (rloc < ne) {
          long hrow = (long)(row_base + rloc) * HP;
          #pragma unroll
          for (int nh = 0; nh < 2; nh++) {
            int hc0 = (n0 + nh * 128 + wc * 32) >> 1;
            float g = acc[mh][nh][m][0][j], u = acc[mh][nh][m][1][j];
            h[hrow + hc0 + fr] = (bf16)((g / (1.f + __expf(-g))) * u);
          }
        }
      }
}

// ---------------- GEMM2: 128x256, BK=32, 4 waves, ring-3 (72 KB) --------------
#define G2_STAGE(SB, T) do { \
    _Pragma("unroll") for (int L_ = 0; L_ < 2; L_++) \
      gload_lds16(aS[L_] + (T) * 32, smem2 + (SB) + w * 1024 + L_ * 512); \
    _Pragma("unroll") for (int L_ = 0; L_ < 4; L_++) \
      gload_lds16(bS[L_] + (T) * 32, smem2 + (SB) + 4096 + w * 2048 + L_ * 512); \
  } while (0)

#define G2_READ0(SB) do { \
    _Pragma("unroll") for (int m_ = 0; m_ < 4; m_++) \
      af[m_] = *(const bf16x8*)&smem2[(SB) + (wr * 64 + m_ * 16 + fr) * 32 + qp]; \
    _Pragma("unroll") for (int n_ = 0; n_ < 4; n_++) \
      bf0[n_] = *(const bf16x8*)&smem2[(SB) + 4096 + (wc * 128 + n_ * 16 + fr) * 32 + qp]; \
  } while (0)

#define G2_MFMA0() do { __builtin_amdgcn_s_setprio(1); \
    _Pragma("unroll") for (int m_ = 0; m_ < 4; m_++) \
    _Pragma("unroll") for (int n_ = 0; n_ < 4; n_++) \
      acc[m_][n_] = __builtin_amdgcn_mfma_f32_16x16x32_bf16(af[m_], bf0[n_], acc[m_][n_], 0, 0, 0); \
    __builtin_amdgcn_s_setprio(0); } while (0)

#define G2_READ1(SB) do { \
    _Pragma("unroll") for (int n_ = 0; n_ < 4; n_++) \
      bf1[n_] = *(const bf16x8*)&smem2[(SB) + 4096 + (wc * 128 + (n_ + 4) * 16 + fr) * 32 + qp]; \
  } while (0)

#define G2_MFMA1() do { __builtin_amdgcn_s_setprio(1); \
    _Pragma("unroll") for (int m_ = 0; m_ < 4; m_++) \
    _Pragma("unroll") for (int n_ = 0; n_ < 4; n_++) \
      acc[m_][n_ + 4] = __builtin_amdgcn_mfma_f32_16x16x32_bf16(af[m_], bf1[n_], acc[m_][n_ + 4], 0, 0, 0); \
    __builtin_amdgcn_s_setprio(0); } while (0)

__global__ __launch_bounds__(256, 2) void gemm2_kernel(
    const bf16* __restrict__ h, const bf16* __restrict__ w2b,
    const int* __restrict__ counts, const int* __restrict__ offs,
    const int* __restrict__ tlist, bf16* __restrict__ y) {
  int te = tlist[blockIdx.x];
  if (te < 0) return;
  int e = te >> 8, tm = te & 255;
  int ne = counts[e];
  int row_base = offs[e];
  int n0 = blockIdx.y * 256;

  __shared__ bf16 smem2[3 * 12288];   // 72 KB: [slot][A 4096 | B 8192]
  int tid = threadIdx.x, w = tid >> 6, lane = tid & 63;
  int wr = w >> 1, wc = w & 1;
  int fr = lane & 15, hi = lane >> 4;
  int qp = (hi ^ ((fr >> 1) & 3)) * 8;
  int srcq = ((lane & 3) ^ ((lane >> 3) & 3)) * 8;
  int srow = lane >> 2;

  f32x4 acc[4][8];
  #pragma unroll
  for (int m = 0; m < 4; m++)
    #pragma unroll
    for (int n = 0; n < 8; n++) acc[m][n] = (f32x4)0.f;

  const bf16* w2e = w2b + (long)e * D_DIM * HP;
  const bf16* aS[2];
  const bf16* bS[4];
  #pragma unroll
  for (int L = 0; L < 2; L++) {
    int ra = row_base + min(tm * 128 + w * 32 + L * 16 + srow, ne - 1);
    aS[L] = h + (long)ra * HP + srcq;
  }
  #pragma unroll
  for (int L = 0; L < 4; L++) {
    int rb = n0 + w * 64 + L * 16 + srow;
    bS[L] = w2e + (long)rb * HP + srcq;
  }

  bf16x8 af[4], bf0[4], bf1[4];

  G2_STAGE(0, 0); G2_STAGE(12288, 1);
  VMCNT(6); BAR();

  int sbC = 0, sbS = 24576;
  for (int t = 0; t < 86; t++) {                      // HP/32 = 88 tiles
    G2_READ0(sbC);
    G2_STAGE(sbS, t + 2);
    BAR();
    G2_MFMA0();
    G2_READ1(sbC);
    G2_MFMA1();
    LGKM0(); VMCNT(6); BAR();
    sbC += 12288; if (sbC > 24576) sbC = 0;
    sbS += 12288; if (sbS > 24576) sbS = 0;
  }
  { G2_READ0(sbC); BAR(); G2_MFMA0(); G2_READ1(sbC); G2_MFMA1(); LGKM0(); VMCNT(0); BAR();
    sbC += 12288; if (sbC > 24576) sbC = 0; }
  { G2_READ0(sbC); G2_MFMA0(); G2_READ1(sbC); G2_MFMA1(); }

  int crow4 = hi * 4;
  #pragma unroll
  for (int m = 0; m < 4; m++)
    #pragma unroll
    for (int j = 0; j < 4; j++) {
      int rloc = tm * 128 + wr * 64 + m * 16 + crow4 + j;
      if (rloc < ne) {
        long yrow = (long)(row_base + rloc) * D_DIM;
        #pragma unroll
        for (int n = 0; n < 8; n++) {
          int col = n0 + wc * 128 + n * 16 + fr;
          y[yrow + col] = (bf16)acc[m][n][j];
        }
      }
    }
}

extern "C" void kernel_launch(void* const* d_in, const int* in_sizes, int n_in,
                              void* d_out, int out_size, void* d_ws, size_t ws_size,
                              hipStream_t stream) {
  const float* x  = (const float*)d_in[0];
  const float* gw = (const float*)d_in[1];
  const float* w1 = (const float*)d_in[2];
  const float* w3 = (const float*)d_in[3];
  const float* w2 = (const float*)d_in[4];
  float* out = (float*)d_out;

  char* ws = (char*)d_ws;
  int*   counts   = (int*)(ws);
  int*   cursor   = (int*)(ws + 64);
  int*   offs     = (int*)(ws + 128);
  int*   tlist    = (int*)(ws + 192);              // 544 B
  int*   tlist2   = (int*)(ws + 768);              // 288 B
  int*   topi     = (int*)(ws + 2048);
  float* topw     = (float*)(ws + 2048 + 65536);
  int*   rowmap   = (int*)(ws + 2048 + 131072);
  float* roww     = (float*)(ws + 2048 + 196608);
  int*   rowoftok = (int*)(ws + 2048 + 262144);
  char*  big      = ws + 2048 + 327680;
  // Bp (92.3 MB) and w2b (46.1 MB) share a region: conv_w2 runs AFTER gemm1.
  bf16* Bp   = (bf16*)big;                                   // [8][5632][1024]
  bf16* w2b  = (bf16*)big;                                   // [8][1024][2816] (alias)
  bf16* Xg   = Bp + (size_t)E_NUM * NP * D_DIM;              // [16384][1024]
  bf16* hbuf = Xg + (size_t)NROWS * D_DIM;                   // [16384][2816]
  bf16* ybuf = Xg;                                           // alias (Xg dead after gemm1)

  hipMemsetAsync((char*)d_out + (size_t)(out_size - 1) * sizeof(float), 0, sizeof(float), stream);
  hipMemsetAsync(ws, 0, 256, stream);   // counts, cursor

  int nbp = E_NUM * NP * 128;
  conv13_kernel<<<(nbp + 255) / 256, 256, 0, stream>>>(w1, w3, Bp);

  router_kernel<<<N_TOK / 4, 256, 0, stream>>>(x, gw, topi, topw, counts);
  tiles_kernel<<<1, 64, 0, stream>>>(counts, offs, tlist, tlist2);
  scatter_kernel<<<(NROWS + 255) / 256, 256, 0, stream>>>(topi, topw, offs, cursor, rowmap, roww, rowoftok);
  gather_kernel<<<NROWS / 4, 256, 0, stream>>>(x, rowmap, Xg);

  dim3 g1(MAXT256, NP / 256);      // (72, 22)
  gemm1_kernel<<<g1, 512, 0, stream>>>(Xg, Bp, counts, offs, tlist2, hbuf);

  int w2n = E_NUM * D_DIM * (HP / 8);
  conv_w2_kernel<<<(w2n + 255) / 256, 256, 0, stream>>>(w2, w2b);

  dim3 g2(MAXTILES, D_DIM / 256);  // (136, 4) = 544 blocks -> full GPU
  gemm2_kernel<<<g2, 256, 0, stream>>>(hbuf, w2b, counts, offs, tlist, ybuf);
  combine_kernel<<<N_TOK / 4, 256, 0, stream>>>(ybuf, rowoftok, topw, out);
}

// Round 9
// 755.636 us; speedup vs baseline: 1.0526x; 1.0043x over previous
//
#include <hip/hip_runtime.h>
#include <hip/hip_bf16.h>

#define N_TOK 8192
#define D_DIM 1024
#define E_NUM 8
#define H_DIM 2730
#define HP    2816     // 22*128 padded h-cols
#define NP    5632     // 2*HP = interleaved B' rows
#define NROWS (N_TOK*2)
#define MAXTILES 136   // sum ceil(ne/128) <= 135

typedef __bf16 bf16;
typedef __bf16 bf16x8 __attribute__((ext_vector_type(8)));
typedef __bf16 bf16x4 __attribute__((ext_vector_type(4)));
typedef float  f32x4  __attribute__((ext_vector_type(4)));

__device__ __forceinline__ void gload_lds16(const bf16* g, bf16* l) {
  __builtin_amdgcn_global_load_lds((const __attribute__((address_space(1))) void*)g,
                                   (__attribute__((address_space(3))) void*)l, 16, 0, 0);
}
#define VMCNT(n) asm volatile("s_waitcnt vmcnt(" #n ")" ::: "memory")
#define LGKM0()  asm volatile("s_waitcnt lgkmcnt(0)" ::: "memory")
#define BAR() __builtin_amdgcn_s_barrier()

// ---------- conv: build interleaved B' [e][5632][1024] bf16 ----------
__global__ void conv13_kernel(const float* __restrict__ w1, const float* __restrict__ w3,
                              bf16* __restrict__ Bp) {
  int i = blockIdx.x * blockDim.x + threadIdx.x;      // (e, r', c8)
  if (i >= E_NUM * NP * 128) return;
  int c8 = i & 127;
  int r  = (i >> 7) % NP;
  int e  = i / (NP * 128);
  int hc = ((r >> 5) << 4) + (r & 15);
  bf16x8 o;
  if (hc < H_DIM) {
    const float* s = (((r >> 4) & 1) ? w3 : w1) + ((long)e * H_DIM + hc) * D_DIM + c8 * 8;
    float4 a0 = ((const float4*)s)[0], a1 = ((const float4*)s)[1];
    o[0]=(bf16)a0.x; o[1]=(bf16)a0.y; o[2]=(bf16)a0.z; o[3]=(bf16)a0.w;
    o[4]=(bf16)a1.x; o[5]=(bf16)a1.y; o[6]=(bf16)a1.z; o[7]=(bf16)a1.w;
  } else {
    #pragma unroll
    for (int j = 0; j < 8; j++) o[j] = (bf16)0.f;
  }
  ((bf16x8*)Bp)[i] = o;
}

__global__ void conv_w2_kernel(const float* __restrict__ src, bf16* __restrict__ dst) {
  int i = blockIdx.x * blockDim.x + threadIdx.x;      // row*(HP/8) + c8
  if (i >= E_NUM * D_DIM * (HP / 8)) return;
  int c8 = i % (HP / 8);
  int row = i / (HP / 8);
  int c = c8 * 8;
  const float* s = src + (long)row * H_DIM + c;
  bf16x8 o;
  #pragma unroll
  for (int j = 0; j < 8; j++) o[j] = (c + j < H_DIM) ? (bf16)s[j] : (bf16)0.f;
  ((bf16x8*)dst)[i] = o;
}

// ---------------- router ----------------
__global__ void router_kernel(const float* __restrict__ x, const float* __restrict__ gw,
                              int* __restrict__ topi, float* __restrict__ topw,
                              int* __restrict__ counts) {
  int t = blockIdx.x * (blockDim.x >> 6) + (threadIdx.x >> 6);
  int lane = threadIdx.x & 63;
  if (t >= N_TOK) return;
  const float* xr = x + (long)t * D_DIM;
  float acc[E_NUM];
  #pragma unroll
  for (int e = 0; e < E_NUM; e++) acc[e] = 0.f;
  for (int j = 0; j < D_DIM / 64; j++) {
    float xv = xr[j * 64 + lane];
    #pragma unroll
    for (int e = 0; e < E_NUM; e++) acc[e] += xv * gw[e * D_DIM + j * 64 + lane];
  }
  #pragma unroll
  for (int e = 0; e < E_NUM; e++) {
    float v = acc[e];
    #pragma unroll
    for (int s = 32; s > 0; s >>= 1) v += __shfl_xor(v, s, 64);
    acc[e] = v;
  }
  if (lane == 0) {
    int b0 = -1, b1 = -1; float v0 = -1e30f, v1 = -1e30f;
    #pragma unroll
    for (int e = 0; e < E_NUM; e++) {
      float v = acc[e];
      if (v > v0) { v1 = v0; b1 = b0; v0 = v; b0 = e; }
      else if (v > v1) { v1 = v; b1 = e; }
    }
    float w0 = 1.f / (1.f + expf(v1 - v0));
    topi[t * 2] = b0; topi[t * 2 + 1] = b1;
    topw[t * 2] = w0; topw[t * 2 + 1] = 1.f - w0;
    atomicAdd(&counts[b0], 1); atomicAdd(&counts[b1], 1);
  }
}

// offsets + 128-row tile list
__global__ void tiles_kernel(const int* __restrict__ counts, int* __restrict__ offs,
                             int* __restrict__ tlist) {
  if (threadIdx.x == 0) {
    int s = 0, idx = 0;
    for (int e = 0; e < E_NUM; e++) {
      offs[e] = s;
      int ne = counts[e];
      s += ne;
      int nt = (ne + 127) >> 7;
      for (int t = 0; t < nt; t++) tlist[idx++] = (e << 8) | t;
    }
    offs[E_NUM] = s;
    for (; idx < MAXTILES; idx++) tlist[idx] = -1;
  }
}

__global__ void scatter_kernel(const int* __restrict__ topi, const float* __restrict__ topw,
                               const int* __restrict__ offs, int* __restrict__ cursor,
                               int* __restrict__ rowmap, float* __restrict__ roww,
                               int* __restrict__ rowoftok) {
  int i = blockIdx.x * blockDim.x + threadIdx.x;
  if (i >= NROWS) return;
  int e = topi[i];
  int pos = atomicAdd(&cursor[e], 1);
  int row = offs[e] + pos;
  rowmap[row] = i >> 1;
  roww[row] = topw[i];
  rowoftok[i] = row;
}

__global__ void gather_kernel(const float* __restrict__ x, const int* __restrict__ rowmap,
                              bf16* __restrict__ Xg) {
  int r = blockIdx.x * (blockDim.x >> 6) + (threadIdx.x >> 6);
  int lane = threadIdx.x & 63;
  if (r >= NROWS) return;
  int t = rowmap[r];
  const float4* src = (const float4*)(x + (long)t * D_DIM);
  bf16x4* dst = (bf16x4*)(Xg + (long)r * D_DIM);
  #pragma unroll
  for (int j = 0; j < 4; j++) {
    float4 v = src[j * 64 + lane];
    bf16x4 o; o[0]=(bf16)v.x; o[1]=(bf16)v.y; o[2]=(bf16)v.z; o[3]=(bf16)v.w;
    dst[j * 64 + lane] = o;
  }
}

// combine: out[t] = w0*y[r0] + w1*y[r1]
__global__ void combine_kernel(const bf16* __restrict__ y, const int* __restrict__ rowoftok,
                               const float* __restrict__ topw, float* __restrict__ out) {
  int t = blockIdx.x * (blockDim.x >> 6) + (threadIdx.x >> 6);
  int lane = threadIdx.x & 63;
  if (t >= N_TOK) return;
  int r0 = rowoftok[t * 2], r1 = rowoftok[t * 2 + 1];
  float w0 = topw[t * 2], w1 = topw[t * 2 + 1];
  const bf16x8* y0 = (const bf16x8*)(y + (long)r0 * D_DIM);
  const bf16x8* y1 = (const bf16x8*)(y + (long)r1 * D_DIM);
  float* o = out + (long)t * D_DIM;
  #pragma unroll
  for (int j = 0; j < 2; j++) {
    bf16x8 a = y0[j * 64 + lane], b = y1[j * 64 + lane];
    float4 v0, v1;
    v0.x = w0*(float)a[0] + w1*(float)b[0]; v0.y = w0*(float)a[1] + w1*(float)b[1];
    v0.z = w0*(float)a[2] + w1*(float)b[2]; v0.w = w0*(float)a[3] + w1*(float)b[3];
    v1.x = w0*(float)a[4] + w1*(float)b[4]; v1.y = w0*(float)a[5] + w1*(float)b[5];
    v1.z = w0*(float)a[6] + w1*(float)b[6]; v1.w = w0*(float)a[7] + w1*(float)b[7];
    float4* op = (float4*)(o + (j * 64 + lane) * 8);
    op[0] = v0; op[1] = v1;
  }
}

// ============ r9 schedule: ring-3, read-early, counted vmcnt, >=2 blocks/CU =====
// Iter t: READ(slot t) | STAGE(t+2 -> slot t+2) | BAR | MFMA | lgkm0 | VMCNT(N) | BAR.
// N = loads-per-stage (one stage-group stays in flight). Cross-block overlap
// absorbs barrier stalls (r5 vs r6-r8 A/B: 2 blocks/CU is the lever).
// Source-quarter swizzle (r3-verified, conflicts=0) unchanged.

// ---------------- GEMM1: 128(M) x 256(B'cols), BK=32, 4 waves, 72 KB ----------
#define G1_STAGE(SB, T) do { \
    _Pragma("unroll") for (int L_ = 0; L_ < 2; L_++) \
      gload_lds16(aS[L_] + (T) * 32, smem + (SB) + w * 1024 + L_ * 512); \
    _Pragma("unroll") for (int L_ = 0; L_ < 4; L_++) \
      gload_lds16(bS[L_] + (T) * 32, smem + (SB) + 4096 + w * 2048 + L_ * 512); \
  } while (0)

#define G1_READ0(SB) do { \
    _Pragma("unroll") for (int m_ = 0; m_ < 4; m_++) \
      af[m_] = *(const bf16x8*)&smem[(SB) + (wr * 64 + m_ * 16 + fr) * 32 + qp]; \
    _Pragma("unroll") for (int q_ = 0; q_ < 4; q_++) \
      bf0[q_] = *(const bf16x8*)&smem[(SB) + 4096 + (wc * 128 + q_ * 16 + fr) * 32 + qp]; \
  } while (0)

#define G1_MFMA0() do { __builtin_amdgcn_s_setprio(1); \
    _Pragma("unroll") for (int m_ = 0; m_ < 4; m_++) \
    _Pragma("unroll") for (int q_ = 0; q_ < 4; q_++) \
      acc[m_][q_] = __builtin_amdgcn_mfma_f32_16x16x32_bf16(af[m_], bf0[q_], acc[m_][q_], 0, 0, 0); \
    __builtin_amdgcn_s_setprio(0); } while (0)

#define G1_READ1(SB) do { \
    _Pragma("unroll") for (int q_ = 0; q_ < 4; q_++) \
      bf1[q_] = *(const bf16x8*)&smem[(SB) + 4096 + (wc * 128 + (q_ + 4) * 16 + fr) * 32 + qp]; \
  } while (0)

#define G1_MFMA1() do { __builtin_amdgcn_s_setprio(1); \
    _Pragma("unroll") for (int m_ = 0; m_ < 4; m_++) \
    _Pragma("unroll") for (int q_ = 0; q_ < 4; q_++) \
      acc[m_][q_ + 4] = __builtin_amdgcn_mfma_f32_16x16x32_bf16(af[m_], bf1[q_], acc[m_][q_ + 4], 0, 0, 0); \
    __builtin_amdgcn_s_setprio(0); } while (0)

__global__ __launch_bounds__(256, 2) void gemm1_kernel(
    const bf16* __restrict__ Xg, const bf16* __restrict__ Bp,
    const int* __restrict__ counts, const int* __restrict__ offs,
    const int* __restrict__ tlist, bf16* __restrict__ h) {
  int te = tlist[blockIdx.x];
  if (te < 0) return;
  int e = te >> 8, tm = te & 255;
  int ne = counts[e];
  int row_base = offs[e];
  int n0 = blockIdx.y * 256;                          // B'-col base

  __shared__ bf16 smem[3 * 12288];                    // 72 KB: [slot][A 4096 | B 8192]
  int tid = threadIdx.x, w = tid >> 6, lane = tid & 63;
  int wr = w >> 1, wc = w & 1;
  int fr = lane & 15, hi = lane >> 4;
  int qp = (hi ^ ((fr >> 1) & 3)) * 8;
  int srcq = ((lane & 3) ^ ((lane >> 3) & 3)) * 8;
  int srow = lane >> 2;

  f32x4 acc[4][8];
  #pragma unroll
  for (int m = 0; m < 4; m++)
    #pragma unroll
    for (int q = 0; q < 8; q++) acc[m][q] = (f32x4)0.f;

  const bf16* Bpe = Bp + (long)e * NP * D_DIM;
  const bf16* aS[2];
  const bf16* bS[4];
  #pragma unroll
  for (int L = 0; L < 2; L++) {
    int ra = row_base + min(tm * 128 + w * 32 + L * 16 + srow, ne - 1);
    aS[L] = Xg + (long)ra * D_DIM + srcq;
  }
  #pragma unroll
  for (int L = 0; L < 4; L++) {
    int rb = n0 + w * 64 + L * 16 + srow;
    bS[L] = Bpe + (long)rb * D_DIM + srcq;
  }

  bf16x8 af[4], bf0[4], bf1[4];

  G1_STAGE(0, 0); G1_STAGE(12288, 1);
  VMCNT(6); BAR();

  int sbC = 0, sbS = 24576;
  for (int t = 0; t < 30; t++) {                      // tiles 0..29; stage 2..31
    G1_READ0(sbC);
    G1_STAGE(sbS, t + 2);
    BAR();
    G1_MFMA0();
    G1_READ1(sbC);
    G1_MFMA1();
    LGKM0(); VMCNT(6); BAR();
    sbC += 12288; if (sbC > 24576) sbC = 0;
    sbS += 12288; if (sbS > 24576) sbS = 0;
  }
  { G1_READ0(sbC); BAR(); G1_MFMA0(); G1_READ1(sbC); G1_MFMA1(); LGKM0(); VMCNT(0); BAR();
    sbC += 12288; if (sbC > 24576) sbC = 0; }
  { G1_READ0(sbC); G1_MFMA0(); G1_READ1(sbC); G1_MFMA1(); }

  // epilogue: q=2p -> gate, q=2p+1 -> up (B' 16-row interleave); h-col block n0/2
  int crow4 = hi * 4;
  #pragma unroll
  for (int m = 0; m < 4; m++)
    #pragma unroll
    for (int j = 0; j < 4; j++) {
      int rloc = tm * 128 + wr * 64 + m * 16 + crow4 + j;
      if (rloc < ne) {
        long hrow = (long)(row_base + rloc) * HP;
        #pragma unroll
        for (int p = 0; p < 4; p++) {
          int col = (n0 >> 1) + wc * 64 + p * 16 + fr;
          float g = acc[m][2 * p][j], u = acc[m][2 * p + 1][j];
          h[hrow + col] = (bf16)((g / (1.f + __expf(-g))) * u);
        }
      }
    }
}

// ---------------- GEMM2: 128x128, BK=32, 4 waves, 48 KB (3 blocks/CU) ---------
#define G2_STAGE(SB, T) do { \
    _Pragma("unroll") for (int L_ = 0; L_ < 2; L_++) \
      gload_lds16(aS[L_] + (T) * 32, smem2 + (SB) + w * 1024 + L_ * 512); \
    _Pragma("unroll") for (int L_ = 0; L_ < 2; L_++) \
      gload_lds16(bS[L_] + (T) * 32, smem2 + (SB) + 4096 + w * 1024 + L_ * 512); \
  } while (0)

#define G2_READ(SB) do { \
    _Pragma("unroll") for (int m_ = 0; m_ < 4; m_++) \
      af[m_] = *(const bf16x8*)&smem2[(SB) + (wr * 64 + m_ * 16 + fr) * 32 + qp]; \
    _Pragma("unroll") for (int n_ = 0; n_ < 4; n_++) \
      bfr[n_] = *(const bf16x8*)&smem2[(SB) + 4096 + (wc * 64 + n_ * 16 + fr) * 32 + qp]; \
  } while (0)

#define G2_MFMA() do { __builtin_amdgcn_s_setprio(1); \
    _Pragma("unroll") for (int m_ = 0; m_ < 4; m_++) \
    _Pragma("unroll") for (int n_ = 0; n_ < 4; n_++) \
      acc[m_][n_] = __builtin_amdgcn_mfma_f32_16x16x32_bf16(af[m_], bfr[n_], acc[m_][n_], 0, 0, 0); \
    __builtin_amdgcn_s_setprio(0); } while (0)

__global__ __launch_bounds__(256, 3) void gemm2_kernel(
    const bf16* __restrict__ h, const bf16* __restrict__ w2b,
    const int* __restrict__ counts, const int* __restrict__ offs,
    const int* __restrict__ tlist, bf16* __restrict__ y) {
  int te = tlist[blockIdx.x];
  if (te < 0) return;
  int e = te >> 8, tm = te & 255;
  int ne = counts[e];
  int row_base = offs[e];
  int n0 = blockIdx.y * 128;

  __shared__ bf16 smem2[3 * 8192];                    // 48 KB: [slot][A 4096 | B 4096]
  int tid = threadIdx.x, w = tid >> 6, lane = tid & 63;
  int wr = w >> 1, wc = w & 1;
  int fr = lane & 15, hi = lane >> 4;
  int qp = (hi ^ ((fr >> 1) & 3)) * 8;
  int srcq = ((lane & 3) ^ ((lane >> 3) & 3)) * 8;
  int srow = lane >> 2;

  f32x4 acc[4][4];
  #pragma unroll
  for (int m = 0; m < 4; m++)
    #pragma unroll
    for (int n = 0; n < 4; n++) acc[m][n] = (f32x4)0.f;

  const bf16* w2e = w2b + (long)e * D_DIM * HP;
  const bf16* aS[2];
  const bf16* bS[2];
  #pragma unroll
  for (int L = 0; L < 2; L++) {
    int ra = row_base + min(tm * 128 + w * 32 + L * 16 + srow, ne - 1);
    aS[L] = h + (long)ra * HP + srcq;
    int rb = n0 + w * 32 + L * 16 + srow;
    bS[L] = w2e + (long)rb * HP + srcq;
  }

  bf16x8 af[4], bfr[4];

  G2_STAGE(0, 0); G2_STAGE(8192, 1);
  VMCNT(4); BAR();

  int sbC = 0, sbS = 16384;
  for (int t = 0; t < 86; t++) {                      // tiles 0..85; stage 2..87
    G2_READ(sbC);
    G2_STAGE(sbS, t + 2);
    BAR();
    G2_MFMA();
    LGKM0(); VMCNT(4); BAR();
    sbC += 8192; if (sbC > 16384) sbC = 0;
    sbS += 8192; if (sbS > 16384) sbS = 0;
  }
  { G2_READ(sbC); BAR(); G2_MFMA(); LGKM0(); VMCNT(0); BAR();
    sbC += 8192; if (sbC > 16384) sbC = 0; }
  { G2_READ(sbC); G2_MFMA(); }

  int crow4 = hi * 4;
  #pragma unroll
  for (int m = 0; m < 4; m++)
    #pragma unroll
    for (int j = 0; j < 4; j++) {
      int rloc = tm * 128 + wr * 64 + m * 16 + crow4 + j;
      if (rloc < ne) {
        long yrow = (long)(row_base + rloc) * D_DIM;
        #pragma unroll
        for (int n = 0; n < 4; n++) {
          int col = n0 + wc * 64 + n * 16 + fr;
          y[yrow + col] = (bf16)acc[m][n][j];
        }
      }
    }
}

extern "C" void kernel_launch(void* const* d_in, const int* in_sizes, int n_in,
                              void* d_out, int out_size, void* d_ws, size_t ws_size,
                              hipStream_t stream) {
  const float* x  = (const float*)d_in[0];
  const float* gw = (const float*)d_in[1];
  const float* w1 = (const float*)d_in[2];
  const float* w3 = (const float*)d_in[3];
  const float* w2 = (const float*)d_in[4];
  float* out = (float*)d_out;

  char* ws = (char*)d_ws;
  int*   counts   = (int*)(ws);
  int*   cursor   = (int*)(ws + 64);
  int*   offs     = (int*)(ws + 128);
  int*   tlist    = (int*)(ws + 192);              // 544 B
  int*   topi     = (int*)(ws + 2048);
  float* topw     = (float*)(ws + 2048 + 65536);
  int*   rowmap   = (int*)(ws + 2048 + 131072);
  float* roww     = (float*)(ws + 2048 + 196608);
  int*   rowoftok = (int*)(ws + 2048 + 262144);
  char*  big      = ws + 2048 + 327680;
  // Bp (92.3 MB) and w2b (46.1 MB) share a region: conv_w2 runs AFTER gemm1.
  bf16* Bp   = (bf16*)big;                                   // [8][5632][1024]
  bf16* w2b  = (bf16*)big;                                   // [8][1024][2816] (alias)
  bf16* Xg   = Bp + (size_t)E_NUM * NP * D_DIM;              // [16384][1024]
  bf16* hbuf = Xg + (size_t)NROWS * D_DIM;                   // [16384][2816]
  bf16* ybuf = Xg;                                           // alias (Xg dead after gemm1)

  hipMemsetAsync((char*)d_out + (size_t)(out_size - 1) * sizeof(float), 0, sizeof(float), stream);
  hipMemsetAsync(ws, 0, 256, stream);   // counts, cursor

  int nbp = E_NUM * NP * 128;
  conv13_kernel<<<(nbp + 255) / 256, 256, 0, stream>>>(w1, w3, Bp);

  router_kernel<<<N_TOK / 4, 256, 0, stream>>>(x, gw, topi, topw, counts);
  tiles_kernel<<<1, 64, 0, stream>>>(counts, offs, tlist);
  scatter_kernel<<<(NROWS + 255) / 256, 256, 0, stream>>>(topi, topw, offs, cursor, rowmap, roww, rowoftok);
  gather_kernel<<<NROWS / 4, 256, 0, stream>>>(x, rowmap, Xg);

  dim3 g1(MAXTILES, NP / 256);     // (136, 22)
  gemm1_kernel<<<g1, 256, 0, stream>>>(Xg, Bp, counts, offs, tlist, hbuf);

  int w2n = E_NUM * D_DIM * (HP / 8);
  conv_w2_kernel<<<(w2n + 255) / 256, 256, 0, stream>>>(w2, w2b);

  dim3 g2(MAXTILES, D_DIM / 128);  // (136, 8) = 1088 blocks, 3 blocks/CU
  gemm2_kernel<<<g2, 256, 0, stream>>>(hbuf, w2b, counts, offs, tlist, ybuf);
  combine_kernel<<<N_TOK / 4, 256, 0, stream>>>(ybuf, rowoftok, topw, out);
}

// Round 10
// 744.667 us; speedup vs baseline: 1.0681x; 1.0147x over previous
//
#include <hip/hip_runtime.h>
#include <hip/hip_bf16.h>

#define N_TOK 8192
#define D_DIM 1024
#define E_NUM 8
#define H_DIM 2730
#define HP    2816     // 22*128 padded h-cols
#define NP    5632     // 2*HP = interleaved B' rows
#define NROWS (N_TOK*2)
#define MAXTILES 136   // sum ceil(ne/128) <= 135

typedef __bf16 bf16;
typedef __bf16 bf16x8 __attribute__((ext_vector_type(8)));
typedef __bf16 bf16x4 __attribute__((ext_vector_type(4)));
typedef float  f32x4  __attribute__((ext_vector_type(4)));

__device__ __forceinline__ void gload_lds16(const bf16* g, bf16* l) {
  __builtin_amdgcn_global_load_lds((const __attribute__((address_space(1))) void*)g,
                                   (__attribute__((address_space(3))) void*)l, 16, 0, 0);
}
#define VMCNT(n) asm volatile("s_waitcnt vmcnt(" #n ")" ::: "memory")
#define LGKM0()  asm volatile("s_waitcnt lgkmcnt(0)" ::: "memory")
#define BAR() __builtin_amdgcn_s_barrier()

// ---------- conv: build interleaved B' [e][5632][1024] bf16 ----------
__global__ void conv13_kernel(const float* __restrict__ w1, const float* __restrict__ w3,
                              bf16* __restrict__ Bp) {
  int i = blockIdx.x * blockDim.x + threadIdx.x;      // (e, r', c8)
  if (i >= E_NUM * NP * 128) return;
  int c8 = i & 127;
  int r  = (i >> 7) % NP;
  int e  = i / (NP * 128);
  int hc = ((r >> 5) << 4) + (r & 15);
  bf16x8 o;
  if (hc < H_DIM) {
    const float* s = (((r >> 4) & 1) ? w3 : w1) + ((long)e * H_DIM + hc) * D_DIM + c8 * 8;
    float4 a0 = ((const float4*)s)[0], a1 = ((const float4*)s)[1];
    o[0]=(bf16)a0.x; o[1]=(bf16)a0.y; o[2]=(bf16)a0.z; o[3]=(bf16)a0.w;
    o[4]=(bf16)a1.x; o[5]=(bf16)a1.y; o[6]=(bf16)a1.z; o[7]=(bf16)a1.w;
  } else {
    #pragma unroll
    for (int j = 0; j < 8; j++) o[j] = (bf16)0.f;
  }
  ((bf16x8*)Bp)[i] = o;
}

__global__ void conv_w2_kernel(const float* __restrict__ src, bf16* __restrict__ dst) {
  int i = blockIdx.x * blockDim.x + threadIdx.x;      // row*(HP/8) + c8
  if (i >= E_NUM * D_DIM * (HP / 8)) return;
  int c8 = i % (HP / 8);
  int row = i / (HP / 8);
  int c = c8 * 8;
  const float* s = src + (long)row * H_DIM + c;
  bf16x8 o;
  #pragma unroll
  for (int j = 0; j < 8; j++) o[j] = (c + j < H_DIM) ? (bf16)s[j] : (bf16)0.f;
  ((bf16x8*)dst)[i] = o;
}

// ---------------- router ----------------
__global__ void router_kernel(const float* __restrict__ x, const float* __restrict__ gw,
                              int* __restrict__ topi, float* __restrict__ topw,
                              int* __restrict__ counts) {
  int t = blockIdx.x * (blockDim.x >> 6) + (threadIdx.x >> 6);
  int lane = threadIdx.x & 63;
  if (t >= N_TOK) return;
  const float* xr = x + (long)t * D_DIM;
  float acc[E_NUM];
  #pragma unroll
  for (int e = 0; e < E_NUM; e++) acc[e] = 0.f;
  for (int j = 0; j < D_DIM / 64; j++) {
    float xv = xr[j * 64 + lane];
    #pragma unroll
    for (int e = 0; e < E_NUM; e++) acc[e] += xv * gw[e * D_DIM + j * 64 + lane];
  }
  #pragma unroll
  for (int e = 0; e < E_NUM; e++) {
    float v = acc[e];
    #pragma unroll
    for (int s = 32; s > 0; s >>= 1) v += __shfl_xor(v, s, 64);
    acc[e] = v;
  }
  if (lane == 0) {
    int b0 = -1, b1 = -1; float v0 = -1e30f, v1 = -1e30f;
    #pragma unroll
    for (int e = 0; e < E_NUM; e++) {
      float v = acc[e];
      if (v > v0) { v1 = v0; b1 = b0; v0 = v; b0 = e; }
      else if (v > v1) { v1 = v; b1 = e; }
    }
    float w0 = 1.f / (1.f + expf(v1 - v0));
    topi[t * 2] = b0; topi[t * 2 + 1] = b1;
    topw[t * 2] = w0; topw[t * 2 + 1] = 1.f - w0;
    atomicAdd(&counts[b0], 1); atomicAdd(&counts[b1], 1);
  }
}

// offsets + 128-row tile list
__global__ void tiles_kernel(const int* __restrict__ counts, int* __restrict__ offs,
                             int* __restrict__ tlist) {
  if (threadIdx.x == 0) {
    int s = 0, idx = 0;
    for (int e = 0; e < E_NUM; e++) {
      offs[e] = s;
      int ne = counts[e];
      s += ne;
      int nt = (ne + 127) >> 7;
      for (int t = 0; t < nt; t++) tlist[idx++] = (e << 8) | t;
    }
    offs[E_NUM] = s;
    for (; idx < MAXTILES; idx++) tlist[idx] = -1;
  }
}

__global__ void scatter_kernel(const int* __restrict__ topi, const float* __restrict__ topw,
                               const int* __restrict__ offs, int* __restrict__ cursor,
                               int* __restrict__ rowmap, float* __restrict__ roww,
                               int* __restrict__ rowoftok) {
  int i = blockIdx.x * blockDim.x + threadIdx.x;
  if (i >= NROWS) return;
  int e = topi[i];
  int pos = atomicAdd(&cursor[e], 1);
  int row = offs[e] + pos;
  rowmap[row] = i >> 1;
  roww[row] = topw[i];
  rowoftok[i] = row;
}

__global__ void gather_kernel(const float* __restrict__ x, const int* __restrict__ rowmap,
                              bf16* __restrict__ Xg) {
  int r = blockIdx.x * (blockDim.x >> 6) + (threadIdx.x >> 6);
  int lane = threadIdx.x & 63;
  if (r >= NROWS) return;
  int t = rowmap[r];
  const float4* src = (const float4*)(x + (long)t * D_DIM);
  bf16x4* dst = (bf16x4*)(Xg + (long)r * D_DIM);
  #pragma unroll
  for (int j = 0; j < 4; j++) {
    float4 v = src[j * 64 + lane];
    bf16x4 o; o[0]=(bf16)v.x; o[1]=(bf16)v.y; o[2]=(bf16)v.z; o[3]=(bf16)v.w;
    dst[j * 64 + lane] = o;
  }
}

// combine: out[t] = w0*y[r0] + w1*y[r1]
__global__ void combine_kernel(const bf16* __restrict__ y, const int* __restrict__ rowoftok,
                               const float* __restrict__ topw, float* __restrict__ out) {
  int t = blockIdx.x * (blockDim.x >> 6) + (threadIdx.x >> 6);
  int lane = threadIdx.x & 63;
  if (t >= N_TOK) return;
  int r0 = rowoftok[t * 2], r1 = rowoftok[t * 2 + 1];
  float w0 = topw[t * 2], w1 = topw[t * 2 + 1];
  const bf16x8* y0 = (const bf16x8*)(y + (long)r0 * D_DIM);
  const bf16x8* y1 = (const bf16x8*)(y + (long)r1 * D_DIM);
  float* o = out + (long)t * D_DIM;
  #pragma unroll
  for (int j = 0; j < 2; j++) {
    bf16x8 a = y0[j * 64 + lane], b = y1[j * 64 + lane];
    float4 v0, v1;
    v0.x = w0*(float)a[0] + w1*(float)b[0]; v0.y = w0*(float)a[1] + w1*(float)b[1];
    v0.z = w0*(float)a[2] + w1*(float)b[2]; v0.w = w0*(float)a[3] + w1*(float)b[3];
    v1.x = w0*(float)a[4] + w1*(float)b[4]; v1.y = w0*(float)a[5] + w1*(float)b[5];
    v1.z = w0*(float)a[6] + w1*(float)b[6]; v1.w = w0*(float)a[7] + w1*(float)b[7];
    float4* op = (float4*)(o + (j * 64 + lane) * 8);
    op[0] = v0; op[1] = v1;
  }
}

// ============ r10: r9 schedule unchanged; 1-D COL-FASTEST grids ============
// Consecutive blocks share the A-panel (read ~once, L2/L3-coalesced); the
// per-expert B working set (11.5 MB gemm1 / 5.77 MB gemm2) stays L2/L3-resident
// across successive row-tiles. Ideal FETCH: gemm1 ~126 MB (was 600), gemm2 ~140.

// ---------------- GEMM1: 128(M) x 256(B'cols), BK=32, 4 waves, 72 KB ----------
#define G1_STAGE(SB, T) do { \
    _Pragma("unroll") for (int L_ = 0; L_ < 2; L_++) \
      gload_lds16(aS[L_] + (T) * 32, smem + (SB) + w * 1024 + L_ * 512); \
    _Pragma("unroll") for (int L_ = 0; L_ < 4; L_++) \
      gload_lds16(bS[L_] + (T) * 32, smem + (SB) + 4096 + w * 2048 + L_ * 512); \
  } while (0)

#define G1_READ0(SB) do { \
    _Pragma("unroll") for (int m_ = 0; m_ < 4; m_++) \
      af[m_] = *(const bf16x8*)&smem[(SB) + (wr * 64 + m_ * 16 + fr) * 32 + qp]; \
    _Pragma("unroll") for (int q_ = 0; q_ < 4; q_++) \
      bf0[q_] = *(const bf16x8*)&smem[(SB) + 4096 + (wc * 128 + q_ * 16 + fr) * 32 + qp]; \
  } while (0)

#define G1_MFMA0() do { __builtin_amdgcn_s_setprio(1); \
    _Pragma("unroll") for (int m_ = 0; m_ < 4; m_++) \
    _Pragma("unroll") for (int q_ = 0; q_ < 4; q_++) \
      acc[m_][q_] = __builtin_amdgcn_mfma_f32_16x16x32_bf16(af[m_], bf0[q_], acc[m_][q_], 0, 0, 0); \
    __builtin_amdgcn_s_setprio(0); } while (0)

#define G1_READ1(SB) do { \
    _Pragma("unroll") for (int q_ = 0; q_ < 4; q_++) \
      bf1[q_] = *(const bf16x8*)&smem[(SB) + 4096 + (wc * 128 + (q_ + 4) * 16 + fr) * 32 + qp]; \
  } while (0)

#define G1_MFMA1() do { __builtin_amdgcn_s_setprio(1); \
    _Pragma("unroll") for (int m_ = 0; m_ < 4; m_++) \
    _Pragma("unroll") for (int q_ = 0; q_ < 4; q_++) \
      acc[m_][q_ + 4] = __builtin_amdgcn_mfma_f32_16x16x32_bf16(af[m_], bf1[q_], acc[m_][q_ + 4], 0, 0, 0); \
    __builtin_amdgcn_s_setprio(0); } while (0)

__global__ __launch_bounds__(256, 2) void gemm1_kernel(
    const bf16* __restrict__ Xg, const bf16* __restrict__ Bp,
    const int* __restrict__ counts, const int* __restrict__ offs,
    const int* __restrict__ tlist, bf16* __restrict__ h) {
  int bid = blockIdx.x;
  int tile = bid / 22, col = bid - tile * 22;         // col-fastest
  int te = tlist[tile];
  if (te < 0) return;
  int e = te >> 8, tm = te & 255;
  int ne = counts[e];
  int row_base = offs[e];
  int n0 = col * 256;                                 // B'-col base

  __shared__ bf16 smem[3 * 12288];                    // 72 KB: [slot][A 4096 | B 8192]
  int tid = threadIdx.x, w = tid >> 6, lane = tid & 63;
  int wr = w >> 1, wc = w & 1;
  int fr = lane & 15, hi = lane >> 4;
  int qp = (hi ^ ((fr >> 1) & 3)) * 8;
  int srcq = ((lane & 3) ^ ((lane >> 3) & 3)) * 8;
  int srow = lane >> 2;

  f32x4 acc[4][8];
  #pragma unroll
  for (int m = 0; m < 4; m++)
    #pragma unroll
    for (int q = 0; q < 8; q++) acc[m][q] = (f32x4)0.f;

  const bf16* Bpe = Bp + (long)e * NP * D_DIM;
  const bf16* aS[2];
  const bf16* bS[4];
  #pragma unroll
  for (int L = 0; L < 2; L++) {
    int ra = row_base + min(tm * 128 + w * 32 + L * 16 + srow, ne - 1);
    aS[L] = Xg + (long)ra * D_DIM + srcq;
  }
  #pragma unroll
  for (int L = 0; L < 4; L++) {
    int rb = n0 + w * 64 + L * 16 + srow;
    bS[L] = Bpe + (long)rb * D_DIM + srcq;
  }

  bf16x8 af[4], bf0[4], bf1[4];

  G1_STAGE(0, 0); G1_STAGE(12288, 1);
  VMCNT(6); BAR();

  int sbC = 0, sbS = 24576;
  for (int t = 0; t < 30; t++) {                      // tiles 0..29; stage 2..31
    G1_READ0(sbC);
    G1_STAGE(sbS, t + 2);
    BAR();
    G1_MFMA0();
    G1_READ1(sbC);
    G1_MFMA1();
    LGKM0(); VMCNT(6); BAR();
    sbC += 12288; if (sbC > 24576) sbC = 0;
    sbS += 12288; if (sbS > 24576) sbS = 0;
  }
  { G1_READ0(sbC); BAR(); G1_MFMA0(); G1_READ1(sbC); G1_MFMA1(); LGKM0(); VMCNT(0); BAR();
    sbC += 12288; if (sbC > 24576) sbC = 0; }
  { G1_READ0(sbC); G1_MFMA0(); G1_READ1(sbC); G1_MFMA1(); }

  // epilogue: q=2p -> gate, q=2p+1 -> up (B' 16-row interleave); h-col block n0/2
  int crow4 = hi * 4;
  #pragma unroll
  for (int m = 0; m < 4; m++)
    #pragma unroll
    for (int j = 0; j < 4; j++) {
      int rloc = tm * 128 + wr * 64 + m * 16 + crow4 + j;
      if (rloc < ne) {
        long hrow = (long)(row_base + rloc) * HP;
        #pragma unroll
        for (int p = 0; p < 4; p++) {
          int col2 = (n0 >> 1) + wc * 64 + p * 16 + fr;
          float g = acc[m][2 * p][j], u = acc[m][2 * p + 1][j];
          h[hrow + col2] = (bf16)((g / (1.f + __expf(-g))) * u);
        }
      }
    }
}

// ---------------- GEMM2: 128x128, BK=32, 4 waves, 48 KB (3 blocks/CU) ---------
#define G2_STAGE(SB, T) do { \
    _Pragma("unroll") for (int L_ = 0; L_ < 2; L_++) \
      gload_lds16(aS[L_] + (T) * 32, smem2 + (SB) + w * 1024 + L_ * 512); \
    _Pragma("unroll") for (int L_ = 0; L_ < 2; L_++) \
      gload_lds16(bS[L_] + (T) * 32, smem2 + (SB) + 4096 + w * 1024 + L_ * 512); \
  } while (0)

#define G2_READ(SB) do { \
    _Pragma("unroll") for (int m_ = 0; m_ < 4; m_++) \
      af[m_] = *(const bf16x8*)&smem2[(SB) + (wr * 64 + m_ * 16 + fr) * 32 + qp]; \
    _Pragma("unroll") for (int n_ = 0; n_ < 4; n_++) \
      bfr[n_] = *(const bf16x8*)&smem2[(SB) + 4096 + (wc * 64 + n_ * 16 + fr) * 32 + qp]; \
  } while (0)

#define G2_MFMA() do { __builtin_amdgcn_s_setprio(1); \
    _Pragma("unroll") for (int m_ = 0; m_ < 4; m_++) \
    _Pragma("unroll") for (int n_ = 0; n_ < 4; n_++) \
      acc[m_][n_] = __builtin_amdgcn_mfma_f32_16x16x32_bf16(af[m_], bfr[n_], acc[m_][n_], 0, 0, 0); \
    __builtin_amdgcn_s_setprio(0); } while (0)

__global__ __launch_bounds__(256, 3) void gemm2_kernel(
    const bf16* __restrict__ h, const bf16* __restrict__ w2b,
    const int* __restrict__ counts, const int* __restrict__ offs,
    const int* __restrict__ tlist, bf16* __restrict__ y) {
  int bid = blockIdx.x;
  int tile = bid >> 3, col = bid & 7;                 // col-fastest
  int te = tlist[tile];
  if (te < 0) return;
  int e = te >> 8, tm = te & 255;
  int ne = counts[e];
  int row_base = offs[e];
  int n0 = col * 128;

  __shared__ bf16 smem2[3 * 8192];                    // 48 KB: [slot][A 4096 | B 4096]
  int tid = threadIdx.x, w = tid >> 6, lane = tid & 63;
  int wr = w >> 1, wc = w & 1;
  int fr = lane & 15, hi = lane >> 4;
  int qp = (hi ^ ((fr >> 1) & 3)) * 8;
  int srcq = ((lane & 3) ^ ((lane >> 3) & 3)) * 8;
  int srow = lane >> 2;

  f32x4 acc[4][4];
  #pragma unroll
  for (int m = 0; m < 4; m++)
    #pragma unroll
    for (int n = 0; n < 4; n++) acc[m][n] = (f32x4)0.f;

  const bf16* w2e = w2b + (long)e * D_DIM * HP;
  const bf16* aS[2];
  const bf16* bS[2];
  #pragma unroll
  for (int L = 0; L < 2; L++) {
    int ra = row_base + min(tm * 128 + w * 32 + L * 16 + srow, ne - 1);
    aS[L] = h + (long)ra * HP + srcq;
    int rb = n0 + w * 32 + L * 16 + srow;
    bS[L] = w2e + (long)rb * HP + srcq;
  }

  bf16x8 af[4], bfr[4];

  G2_STAGE(0, 0); G2_STAGE(8192, 1);
  VMCNT(4); BAR();

  int sbC = 0, sbS = 16384;
  for (int t = 0; t < 86; t++) {                      // tiles 0..85; stage 2..87
    G2_READ(sbC);
    G2_STAGE(sbS, t + 2);
    BAR();
    G2_MFMA();
    LGKM0(); VMCNT(4); BAR();
    sbC += 8192; if (sbC > 16384) sbC = 0;
    sbS += 8192; if (sbS > 16384) sbS = 0;
  }
  { G2_READ(sbC); BAR(); G2_MFMA(); LGKM0(); VMCNT(0); BAR();
    sbC += 8192; if (sbC > 16384) sbC = 0; }
  { G2_READ(sbC); G2_MFMA(); }

  int crow4 = hi * 4;
  #pragma unroll
  for (int m = 0; m < 4; m++)
    #pragma unroll
    for (int j = 0; j < 4; j++) {
      int rloc = tm * 128 + wr * 64 + m * 16 + crow4 + j;
      if (rloc < ne) {
        long yrow = (long)(row_base + rloc) * D_DIM;
        #pragma unroll
        for (int n = 0; n < 4; n++) {
          int col2 = n0 + wc * 64 + n * 16 + fr;
          y[yrow + col2] = (bf16)acc[m][n][j];
        }
      }
    }
}

extern "C" void kernel_launch(void* const* d_in, const int* in_sizes, int n_in,
                              void* d_out, int out_size, void* d_ws, size_t ws_size,
                              hipStream_t stream) {
  const float* x  = (const float*)d_in[0];
  const float* gw = (const float*)d_in[1];
  const float* w1 = (const float*)d_in[2];
  const float* w3 = (const float*)d_in[3];
  const float* w2 = (const float*)d_in[4];
  float* out = (float*)d_out;

  char* ws = (char*)d_ws;
  int*   counts   = (int*)(ws);
  int*   cursor   = (int*)(ws + 64);
  int*   offs     = (int*)(ws + 128);
  int*   tlist    = (int*)(ws + 192);              // 544 B
  int*   topi     = (int*)(ws + 2048);
  float* topw     = (float*)(ws + 2048 + 65536);
  int*   rowmap   = (int*)(ws + 2048 + 131072);
  float* roww     = (float*)(ws + 2048 + 196608);
  int*   rowoftok = (int*)(ws + 2048 + 262144);
  char*  big      = ws + 2048 + 327680;
  // Bp (92.3 MB) and w2b (46.1 MB) share a region: conv_w2 runs AFTER gemm1.
  bf16* Bp   = (bf16*)big;                                   // [8][5632][1024]
  bf16* w2b  = (bf16*)big;                                   // [8][1024][2816] (alias)
  bf16* Xg   = Bp + (size_t)E_NUM * NP * D_DIM;              // [16384][1024]
  bf16* hbuf = Xg + (size_t)NROWS * D_DIM;                   // [16384][2816]
  bf16* ybuf = Xg;                                           // alias (Xg dead after gemm1)

  hipMemsetAsync((char*)d_out + (size_t)(out_size - 1) * sizeof(float), 0, sizeof(float), stream);
  hipMemsetAsync(ws, 0, 256, stream);   // counts, cursor

  int nbp = E_NUM * NP * 128;
  conv13_kernel<<<(nbp + 255) / 256, 256, 0, stream>>>(w1, w3, Bp);

  router_kernel<<<N_TOK / 4, 256, 0, stream>>>(x, gw, topi, topw, counts);
  tiles_kernel<<<1, 64, 0, stream>>>(counts, offs, tlist);
  scatter_kernel<<<(NROWS + 255) / 256, 256, 0, stream>>>(topi, topw, offs, cursor, rowmap, roww, rowoftok);
  gather_kernel<<<NROWS / 4, 256, 0, stream>>>(x, rowmap, Xg);

  gemm1_kernel<<<MAXTILES * 22, 256, 0, stream>>>(Xg, Bp, counts, offs, tlist, hbuf);

  int w2n = E_NUM * D_DIM * (HP / 8);
  conv_w2_kernel<<<(w2n + 255) / 256, 256, 0, stream>>>(w2, w2b);

  gemm2_kernel<<<MAXTILES * 8, 256, 0, stream>>>(hbuf, w2b, counts, offs, tlist, ybuf);
  combine_kernel<<<N_TOK / 4, 256, 0, stream>>>(ybuf, rowoftok, topw, out);
}

// Round 11
// 724.606 us; speedup vs baseline: 1.0977x; 1.0277x over previous
//
#include <hip/hip_runtime.h>
#include <hip/hip_bf16.h>

#define N_TOK 8192
#define D_DIM 1024
#define E_NUM 8
#define H_DIM 2730
#define HP    2816     // 22*128 padded h-cols
#define NP    5632     // 2*HP = interleaved B' rows
#define NROWS (N_TOK*2)
#define MAXTILES 136   // sum ceil(ne/128) <= 135
#define MAXT256  72    // sum ceil(ne/256) <= 71

typedef __bf16 bf16;
typedef __bf16 bf16x8 __attribute__((ext_vector_type(8)));
typedef __bf16 bf16x4 __attribute__((ext_vector_type(4)));
typedef float  f32x4  __attribute__((ext_vector_type(4)));

__device__ __forceinline__ void gload_lds16(const bf16* g, bf16* l) {
  __builtin_amdgcn_global_load_lds((const __attribute__((address_space(1))) void*)g,
                                   (__attribute__((address_space(3))) void*)l, 16, 0, 0);
}
#define VMCNT(n) asm volatile("s_waitcnt vmcnt(" #n ")" ::: "memory")
#define LGKM0()  asm volatile("s_waitcnt lgkmcnt(0)" ::: "memory")
#define BAR() __builtin_amdgcn_s_barrier()

// ---------- conv: build interleaved B' [e][5632][1024] bf16 ----------
__global__ void conv13_kernel(const float* __restrict__ w1, const float* __restrict__ w3,
                              bf16* __restrict__ Bp) {
  int i = blockIdx.x * blockDim.x + threadIdx.x;      // (e, r', c8)
  if (i >= E_NUM * NP * 128) return;
  int c8 = i & 127;
  int r  = (i >> 7) % NP;
  int e  = i / (NP * 128);
  int hc = ((r >> 5) << 4) + (r & 15);
  bf16x8 o;
  if (hc < H_DIM) {
    const float* s = (((r >> 4) & 1) ? w3 : w1) + ((long)e * H_DIM + hc) * D_DIM + c8 * 8;
    float4 a0 = ((const float4*)s)[0], a1 = ((const float4*)s)[1];
    o[0]=(bf16)a0.x; o[1]=(bf16)a0.y; o[2]=(bf16)a0.z; o[3]=(bf16)a0.w;
    o[4]=(bf16)a1.x; o[5]=(bf16)a1.y; o[6]=(bf16)a1.z; o[7]=(bf16)a1.w;
  } else {
    #pragma unroll
    for (int j = 0; j < 8; j++) o[j] = (bf16)0.f;
  }
  ((bf16x8*)Bp)[i] = o;
}

__global__ void conv_w2_kernel(const float* __restrict__ src, bf16* __restrict__ dst) {
  int i = blockIdx.x * blockDim.x + threadIdx.x;      // row*(HP/8) + c8
  if (i >= E_NUM * D_DIM * (HP / 8)) return;
  int c8 = i % (HP / 8);
  int row = i / (HP / 8);
  int c = c8 * 8;
  const float* s = src + (long)row * H_DIM + c;
  bf16x8 o;
  #pragma unroll
  for (int j = 0; j < 8; j++) o[j] = (c + j < H_DIM) ? (bf16)s[j] : (bf16)0.f;
  ((bf16x8*)dst)[i] = o;
}

// ---------------- router ----------------
__global__ void router_kernel(const float* __restrict__ x, const float* __restrict__ gw,
                              int* __restrict__ topi, float* __restrict__ topw,
                              int* __restrict__ counts) {
  int t = blockIdx.x * (blockDim.x >> 6) + (threadIdx.x >> 6);
  int lane = threadIdx.x & 63;
  if (t >= N_TOK) return;
  const float* xr = x + (long)t * D_DIM;
  float acc[E_NUM];
  #pragma unroll
  for (int e = 0; e < E_NUM; e++) acc[e] = 0.f;
  for (int j = 0; j < D_DIM / 64; j++) {
    float xv = xr[j * 64 + lane];
    #pragma unroll
    for (int e = 0; e < E_NUM; e++) acc[e] += xv * gw[e * D_DIM + j * 64 + lane];
  }
  #pragma unroll
  for (int e = 0; e < E_NUM; e++) {
    float v = acc[e];
    #pragma unroll
    for (int s = 32; s > 0; s >>= 1) v += __shfl_xor(v, s, 64);
    acc[e] = v;
  }
  if (lane == 0) {
    int b0 = -1, b1 = -1; float v0 = -1e30f, v1 = -1e30f;
    #pragma unroll
    for (int e = 0; e < E_NUM; e++) {
      float v = acc[e];
      if (v > v0) { v1 = v0; b1 = b0; v0 = v; b0 = e; }
      else if (v > v1) { v1 = v; b1 = e; }
    }
    float w0 = 1.f / (1.f + expf(v1 - v0));
    topi[t * 2] = b0; topi[t * 2 + 1] = b1;
    topw[t * 2] = w0; topw[t * 2 + 1] = 1.f - w0;
    atomicAdd(&counts[b0], 1); atomicAdd(&counts[b1], 1);
  }
}

// offsets + 128-row tile list (gemm2) + 256-row tile list (gemm1)
__global__ void tiles_kernel(const int* __restrict__ counts, int* __restrict__ offs,
                             int* __restrict__ tlist, int* __restrict__ tlist2) {
  if (threadIdx.x == 0) {
    int s = 0, idx = 0, idx2 = 0;
    for (int e = 0; e < E_NUM; e++) {
      offs[e] = s;
      int ne = counts[e];
      s += ne;
      int nt = (ne + 127) >> 7;
      for (int t = 0; t < nt; t++) tlist[idx++] = (e << 8) | t;
      int nt2 = (ne + 255) >> 8;
      for (int t = 0; t < nt2; t++) tlist2[idx2++] = (e << 8) | t;
    }
    offs[E_NUM] = s;
    for (; idx < MAXTILES; idx++) tlist[idx] = -1;
    for (; idx2 < MAXT256; idx2++) tlist2[idx2] = -1;
  }
}

__global__ void scatter_kernel(const int* __restrict__ topi, const float* __restrict__ topw,
                               const int* __restrict__ offs, int* __restrict__ cursor,
                               int* __restrict__ rowmap, float* __restrict__ roww,
                               int* __restrict__ rowoftok) {
  int i = blockIdx.x * blockDim.x + threadIdx.x;
  if (i >= NROWS) return;
  int e = topi[i];
  int pos = atomicAdd(&cursor[e], 1);
  int row = offs[e] + pos;
  rowmap[row] = i >> 1;
  roww[row] = topw[i];
  rowoftok[i] = row;
}

__global__ void gather_kernel(const float* __restrict__ x, const int* __restrict__ rowmap,
                              bf16* __restrict__ Xg) {
  int r = blockIdx.x * (blockDim.x >> 6) + (threadIdx.x >> 6);
  int lane = threadIdx.x & 63;
  if (r >= NROWS) return;
  int t = rowmap[r];
  const float4* src = (const float4*)(x + (long)t * D_DIM);
  bf16x4* dst = (bf16x4*)(Xg + (long)r * D_DIM);
  #pragma unroll
  for (int j = 0; j < 4; j++) {
    float4 v = src[j * 64 + lane];
    bf16x4 o; o[0]=(bf16)v.x; o[1]=(bf16)v.y; o[2]=(bf16)v.z; o[3]=(bf16)v.w;
    dst[j * 64 + lane] = o;
  }
}

// combine: out[t] = w0*y[r0] + w1*y[r1]
__global__ void combine_kernel(const bf16* __restrict__ y, const int* __restrict__ rowoftok,
                               const float* __restrict__ topw, float* __restrict__ out) {
  int t = blockIdx.x * (blockDim.x >> 6) + (threadIdx.x >> 6);
  int lane = threadIdx.x & 63;
  if (t >= N_TOK) return;
  int r0 = rowoftok[t * 2], r1 = rowoftok[t * 2 + 1];
  float w0 = topw[t * 2], w1 = topw[t * 2 + 1];
  const bf16x8* y0 = (const bf16x8*)(y + (long)r0 * D_DIM);
  const bf16x8* y1 = (const bf16x8*)(y + (long)r1 * D_DIM);
  float* o = out + (long)t * D_DIM;
  #pragma unroll
  for (int j = 0; j < 2; j++) {
    bf16x8 a = y0[j * 64 + lane], b = y1[j * 64 + lane];
    float4 v0, v1;
    v0.x = w0*(float)a[0] + w1*(float)b[0]; v0.y = w0*(float)a[1] + w1*(float)b[1];
    v0.z = w0*(float)a[2] + w1*(float)b[2]; v0.w = w0*(float)a[3] + w1*(float)b[3];
    v1.x = w0*(float)a[4] + w1*(float)b[4]; v1.y = w0*(float)a[5] + w1*(float)b[5];
    v1.z = w0*(float)a[6] + w1*(float)b[6]; v1.w = w0*(float)a[7] + w1*(float)b[7];
    float4* op = (float4*)(o + (j * 64 + lane) * 8);
    op[0] = v0; op[1] = v1;
  }
}

// ======== r11: same ring-3/read-early/counted-vmcnt schedule; new tile aspects ======
// gemm1 256Mx128N' halves the B-panel re-read count (71 row-tiles vs 135);
// gemm2 reverts to r8's 128Mx256N (r8->r9 A/B: 128x128 cost +33us).

// ---------------- GEMM1: 256(M) x 128(B'cols), BK=32, 4 waves, 72 KB ----------
// LDS slot: A 8192 elems @0 (256 rows), B 4096 elems @8192 (128 rows).
#define G1_STAGE(SB, T) do { \
    _Pragma("unroll") for (int L_ = 0; L_ < 4; L_++) \
      gload_lds16(aS[L_] + (T) * 32, smem + (SB) + w * 2048 + L_ * 512); \
    _Pragma("unroll") for (int L_ = 0; L_ < 2; L_++) \
      gload_lds16(bS[L_] + (T) * 32, smem + (SB) + 8192 + w * 1024 + L_ * 512); \
  } while (0)

#define G1_READ0(SB) do { \
    _Pragma("unroll") for (int m_ = 0; m_ < 4; m_++) \
      af[m_] = *(const bf16x8*)&smem[(SB) + (w * 64 + m_ * 16 + fr) * 32 + qp]; \
    _Pragma("unroll") for (int q_ = 0; q_ < 4; q_++) \
      bf0[q_] = *(const bf16x8*)&smem[(SB) + 8192 + (q_ * 16 + fr) * 32 + qp]; \
  } while (0)

#define G1_MFMA0() do { __builtin_amdgcn_s_setprio(1); \
    _Pragma("unroll") for (int m_ = 0; m_ < 4; m_++) \
    _Pragma("unroll") for (int q_ = 0; q_ < 4; q_++) \
      acc[m_][q_] = __builtin_amdgcn_mfma_f32_16x16x32_bf16(af[m_], bf0[q_], acc[m_][q_], 0, 0, 0); \
    __builtin_amdgcn_s_setprio(0); } while (0)

#define G1_READ1(SB) do { \
    _Pragma("unroll") for (int q_ = 0; q_ < 4; q_++) \
      bf1[q_] = *(const bf16x8*)&smem[(SB) + 8192 + ((q_ + 4) * 16 + fr) * 32 + qp]; \
  } while (0)

#define G1_MFMA1() do { __builtin_amdgcn_s_setprio(1); \
    _Pragma("unroll") for (int m_ = 0; m_ < 4; m_++) \
    _Pragma("unroll") for (int q_ = 0; q_ < 4; q_++) \
      acc[m_][q_ + 4] = __builtin_amdgcn_mfma_f32_16x16x32_bf16(af[m_], bf1[q_], acc[m_][q_ + 4], 0, 0, 0); \
    __builtin_amdgcn_s_setprio(0); } while (0)

__global__ __launch_bounds__(256, 2) void gemm1_kernel(
    const bf16* __restrict__ Xg, const bf16* __restrict__ Bp,
    const int* __restrict__ counts, const int* __restrict__ offs,
    const int* __restrict__ tlist2, bf16* __restrict__ h) {
  int bid = blockIdx.x;
  int tile = bid / 44, col = bid - tile * 44;         // col-fastest over 44 cols
  int te = tlist2[tile];
  if (te < 0) return;
  int e = te >> 8, tm = te & 255;
  int ne = counts[e];
  int row_base = offs[e];
  int n0 = col * 128;                                 // B'-col base

  __shared__ bf16 smem[3 * 12288];                    // 72 KB: [slot][A 8192 | B 4096]
  int tid = threadIdx.x, w = tid >> 6, lane = tid & 63;
  int fr = lane & 15, hi = lane >> 4;
  int qp = (hi ^ ((fr >> 1) & 3)) * 8;
  int srcq = ((lane & 3) ^ ((lane >> 3) & 3)) * 8;
  int srow = lane >> 2;

  f32x4 acc[4][8];
  #pragma unroll
  for (int m = 0; m < 4; m++)
    #pragma unroll
    for (int q = 0; q < 8; q++) acc[m][q] = (f32x4)0.f;

  const bf16* Bpe = Bp + (long)e * NP * D_DIM;
  const bf16* aS[4];
  const bf16* bS[2];
  #pragma unroll
  for (int L = 0; L < 4; L++) {
    int ra = row_base + min(tm * 256 + w * 64 + L * 16 + srow, ne - 1);
    aS[L] = Xg + (long)ra * D_DIM + srcq;
  }
  #pragma unroll
  for (int L = 0; L < 2; L++) {
    int rb = n0 + w * 32 + L * 16 + srow;
    bS[L] = Bpe + (long)rb * D_DIM + srcq;
  }

  bf16x8 af[4], bf0[4], bf1[4];

  G1_STAGE(0, 0); G1_STAGE(12288, 1);
  VMCNT(6); BAR();

  int sbC = 0, sbS = 24576;
  for (int t = 0; t < 30; t++) {                      // tiles 0..29; stage 2..31
    G1_READ0(sbC);
    G1_STAGE(sbS, t + 2);
    BAR();
    G1_MFMA0();
    G1_READ1(sbC);
    G1_MFMA1();
    LGKM0(); VMCNT(6); BAR();
    sbC += 12288; if (sbC > 24576) sbC = 0;
    sbS += 12288; if (sbS > 24576) sbS = 0;
  }
  { G1_READ0(sbC); BAR(); G1_MFMA0(); G1_READ1(sbC); G1_MFMA1(); LGKM0(); VMCNT(0); BAR();
    sbC += 12288; if (sbC > 24576) sbC = 0; }
  { G1_READ0(sbC); G1_MFMA0(); G1_READ1(sbC); G1_MFMA1(); }

  // epilogue: q=2p -> gate, q=2p+1 -> up (B' 16-row interleave); h-col base n0/2
  int crow4 = hi * 4;
  #pragma unroll
  for (int m = 0; m < 4; m++)
    #pragma unroll
    for (int j = 0; j < 4; j++) {
      int rloc = tm * 256 + w * 64 + m * 16 + crow4 + j;
      if (rloc < ne) {
        long hrow = (long)(row_base + rloc) * HP;
        #pragma unroll
        for (int p = 0; p < 4; p++) {
          int col2 = (n0 >> 1) + p * 16 + fr;
          float g = acc[m][2 * p][j], u = acc[m][2 * p + 1][j];
          h[hrow + col2] = (bf16)((g / (1.f + __expf(-g))) * u);
        }
      }
    }
}

// ---------------- GEMM2: 128(M) x 256(N), BK=32, 4 waves, 72 KB ---------------
// LDS slot: A 4096 elems @0 (128 rows), B 8192 elems @4096 (256 rows).
#define G2_STAGE(SB, T) do { \
    _Pragma("unroll") for (int L_ = 0; L_ < 2; L_++) \
      gload_lds16(aS[L_] + (T) * 32, smem2 + (SB) + w * 1024 + L_ * 512); \
    _Pragma("unroll") for (int L_ = 0; L_ < 4; L_++) \
      gload_lds16(bS[L_] + (T) * 32, smem2 + (SB) + 4096 + (L_ * 4 + w) * 512); \
  } while (0)

#define G2_READ0(SB) do { \
    _Pragma("unroll") for (int m_ = 0; m_ < 4; m_++) \
      af[m_] = *(const bf16x8*)&smem2[(SB) + (wr * 64 + m_ * 16 + fr) * 32 + qp]; \
    _Pragma("unroll") for (int n_ = 0; n_ < 4; n_++) \
      bf0[n_] = *(const bf16x8*)&smem2[(SB) + 4096 + (wc * 128 + n_ * 16 + fr) * 32 + qp]; \
  } while (0)

#define G2_MFMA0() do { __builtin_amdgcn_s_setprio(1); \
    _Pragma("unroll") for (int m_ = 0; m_ < 4; m_++) \
    _Pragma("unroll") for (int n_ = 0; n_ < 4; n_++) \
      acc[m_][n_] = __builtin_amdgcn_mfma_f32_16x16x32_bf16(af[m_], bf0[n_], acc[m_][n_], 0, 0, 0); \
    __builtin_amdgcn_s_setprio(0); } while (0)

#define G2_READ1(SB) do { \
    _Pragma("unroll") for (int n_ = 0; n_ < 4; n_++) \
      bf1[n_] = *(const bf16x8*)&smem2[(SB) + 4096 + (wc * 128 + (n_ + 4) * 16 + fr) * 32 + qp]; \
  } while (0)

#define G2_MFMA1() do { __builtin_amdgcn_s_setprio(1); \
    _Pragma("unroll") for (int m_ = 0; m_ < 4; m_++) \
    _Pragma("unroll") for (int n_ = 0; n_ < 4; n_++) \
      acc[m_][n_ + 4] = __builtin_amdgcn_mfma_f32_16x16x32_bf16(af[m_], bf1[n_], acc[m_][n_ + 4], 0, 0, 0); \
    __builtin_amdgcn_s_setprio(0); } while (0)

__global__ __launch_bounds__(256, 2) void gemm2_kernel(
    const bf16* __restrict__ h, const bf16* __restrict__ w2b,
    const int* __restrict__ counts, const int* __restrict__ offs,
    const int* __restrict__ tlist, bf16* __restrict__ y) {
  int bid = blockIdx.x;
  int tile = bid >> 2, col = bid & 3;                 // col-fastest over 4 cols
  int te = tlist[tile];
  if (te < 0) return;
  int e = te >> 8, tm = te & 255;
  int ne = counts[e];
  int row_base = offs[e];
  int n0 = col * 256;

  __shared__ bf16 smem2[3 * 12288];                   // 72 KB: [slot][A 4096 | B 8192]
  int tid = threadIdx.x, w = tid >> 6, lane = tid & 63;
  int wr = w >> 1, wc = w & 1;
  int fr = lane & 15, hi = lane >> 4;
  int qp = (hi ^ ((fr >> 1) & 3)) * 8;
  int srcq = ((lane & 3) ^ ((lane >> 3) & 3)) * 8;
  int srow = lane >> 2;

  f32x4 acc[4][8];
  #pragma unroll
  for (int m = 0; m < 4; m++)
    #pragma unroll
    for (int n = 0; n < 8; n++) acc[m][n] = (f32x4)0.f;

  const bf16* w2e = w2b + (long)e * D_DIM * HP;
  const bf16* aS[2];
  const bf16* bS[4];
  #pragma unroll
  for (int L = 0; L < 2; L++) {
    int ra = row_base + min(tm * 128 + w * 32 + L * 16 + srow, ne - 1);
    aS[L] = h + (long)ra * HP + srcq;
  }
  #pragma unroll
  for (int L = 0; L < 4; L++) {
    int rb = n0 + (L * 4 + w) * 16 + srow;
    bS[L] = w2e + (long)rb * HP + srcq;
  }

  bf16x8 af[4], bf0[4], bf1[4];

  G2_STAGE(0, 0); G2_STAGE(12288, 1);
  VMCNT(6); BAR();

  int sbC = 0, sbS = 24576;
  for (int t = 0; t < 86; t++) {                      // tiles 0..85; stage 2..87
    G2_READ0(sbC);
    G2_STAGE(sbS, t + 2);
    BAR();
    G2_MFMA0();
    G2_READ1(sbC);
    G2_MFMA1();
    LGKM0(); VMCNT(6); BAR();
    sbC += 12288; if (sbC > 24576) sbC = 0;
    sbS += 12288; if (sbS > 24576) sbS = 0;
  }
  { G2_READ0(sbC); BAR(); G2_MFMA0(); G2_READ1(sbC); G2_MFMA1(); LGKM0(); VMCNT(0); BAR();
    sbC += 12288; if (sbC > 24576) sbC = 0; }
  { G2_READ0(sbC); G2_MFMA0(); G2_READ1(sbC); G2_MFMA1(); }

  int crow4 = hi * 4;
  #pragma unroll
  for (int m = 0; m < 4; m++)
    #pragma unroll
    for (int j = 0; j < 4; j++) {
      int rloc = tm * 128 + wr * 64 + m * 16 + crow4 + j;
      if (rloc < ne) {
        long yrow = (long)(row_base + rloc) * D_DIM;
        #pragma unroll
        for (int n = 0; n < 8; n++) {
          int col2 = n0 + wc * 128 + n * 16 + fr;
          y[yrow + col2] = (bf16)acc[m][n][j];
        }
      }
    }
}

extern "C" void kernel_launch(void* const* d_in, const int* in_sizes, int n_in,
                              void* d_out, int out_size, void* d_ws, size_t ws_size,
                              hipStream_t stream) {
  const float* x  = (const float*)d_in[0];
  const float* gw = (const float*)d_in[1];
  const float* w1 = (const float*)d_in[2];
  const float* w3 = (const float*)d_in[3];
  const float* w2 = (const float*)d_in[4];
  float* out = (float*)d_out;

  char* ws = (char*)d_ws;
  int*   counts   = (int*)(ws);
  int*   cursor   = (int*)(ws + 64);
  int*   offs     = (int*)(ws + 128);
  int*   tlist    = (int*)(ws + 192);              // 544 B
  int*   tlist2   = (int*)(ws + 768);              // 288 B
  int*   topi     = (int*)(ws + 2048);
  float* topw     = (float*)(ws + 2048 + 65536);
  int*   rowmap   = (int*)(ws + 2048 + 131072);
  float* roww     = (float*)(ws + 2048 + 196608);
  int*   rowoftok = (int*)(ws + 2048 + 262144);
  char*  big      = ws + 2048 + 327680;
  // Bp (92.3 MB) and w2b (46.1 MB) share a region: conv_w2 runs AFTER gemm1.
  bf16* Bp   = (bf16*)big;                                   // [8][5632][1024]
  bf16* w2b  = (bf16*)big;                                   // [8][1024][2816] (alias)
  bf16* Xg   = Bp + (size_t)E_NUM * NP * D_DIM;              // [16384][1024]
  bf16* hbuf = Xg + (size_t)NROWS * D_DIM;                   // [16384][2816]
  bf16* ybuf = Xg;                                           // alias (Xg dead after gemm1)

  hipMemsetAsync((char*)d_out + (size_t)(out_size - 1) * sizeof(float), 0, sizeof(float), stream);
  hipMemsetAsync(ws, 0, 256, stream);   // counts, cursor

  int nbp = E_NUM * NP * 128;
  conv13_kernel<<<(nbp + 255) / 256, 256, 0, stream>>>(w1, w3, Bp);

  router_kernel<<<N_TOK / 4, 256, 0, stream>>>(x, gw, topi, topw, counts);
  tiles_kernel<<<1, 64, 0, stream>>>(counts, offs, tlist, tlist2);
  scatter_kernel<<<(NROWS + 255) / 256, 256, 0, stream>>>(topi, topw, offs, cursor, rowmap, roww, rowoftok);
  gather_kernel<<<NROWS / 4, 256, 0, stream>>>(x, rowmap, Xg);

  gemm1_kernel<<<MAXT256 * 44, 256, 0, stream>>>(Xg, Bp, counts, offs, tlist2, hbuf);

  int w2n = E_NUM * D_DIM * (HP / 8);
  conv_w2_kernel<<<(w2n + 255) / 256, 256, 0, stream>>>(w2, w2b);

  gemm2_kernel<<<MAXTILES * 4, 256, 0, stream>>>(hbuf, w2b, counts, offs, tlist, ybuf);
  combine_kernel<<<N_TOK / 4, 256, 0, stream>>>(ybuf, rowoftok, topw, out);
}